// Round 15
// baseline (502.432 us; speedup 1.0000x reference)
//
#include <hip/hip_runtime.h>
#include <math.h>

// MixedHead: B=16,T=256 -> BT=4096; INP=1536; E=512; H=8; N=16; D=64.
#define BTOT 4096
#define INP  1536
#define EDIM 512
#define NTOK 16
#define KVW  16384   // 2*E*N
#define ENW  8192    // E*N
#define FFH  1024    // 2*E
#define NDOT 2048    // 16 targets x 128 (h,m)

typedef __attribute__((ext_vector_type(8))) __bf16 bf16x8;
typedef __attribute__((ext_vector_type(4))) float f32x4;

__device__ __forceinline__ ushort f2bf(float f) {
    union { float f; unsigned u; } v; v.f = f;
    unsigned r = v.u + 0x7fffu + ((v.u >> 16) & 1u);
    return (ushort)(r >> 16);
}
__device__ __forceinline__ float bf2f(ushort h) {
    union { unsigned u; float f; } v; v.u = ((unsigned)h) << 16;
    return v.f;
}

// ---------------------------------------------------------------------------
// Transpose f32 [R][ld] (cols c0..) -> bf16 [C][R]. 10 jobs, one launch (r8).
// ---------------------------------------------------------------------------
__device__ __forceinline__ void transpose_body(
    const float* in, int ld, int c0, int R, ushort* out,
    int bx, int by, int tid)
{
    __shared__ float t[64][65];
    const int bc = bx * 64 + c0;
    const int br = by * 64;
#pragma unroll
    for (int it = 0; it < 16; ++it) {
        int idx = tid + it * 256;
        int r = idx >> 6, c = idx & 63;
        t[r][c] = in[(size_t)(br + r) * ld + bc + c];
    }
    __syncthreads();
    const int C0 = bx * 64;
#pragma unroll
    for (int it = 0; it < 4; ++it) {
        int idx = tid + it * 256;          // 1024 = 64 cols x 16 row-quads
        int cc = idx >> 4, rp = idx & 15;
        uint2 w2;
        w2.x = f2bf(t[4 * rp + 0][cc]) | ((unsigned)f2bf(t[4 * rp + 1][cc]) << 16);
        w2.y = f2bf(t[4 * rp + 2][cc]) | ((unsigned)f2bf(t[4 * rp + 3][cc]) << 16);
        *reinterpret_cast<uint2*>(out + (size_t)(C0 + cc) * R + br + 4 * rp) = w2;
    }
}

struct TJob { const float* in; ushort* out; int ld, c0, R, gbx, boffs; };
struct TJobs { TJob j[10]; };

__global__ __launch_bounds__(256) void transpose_all_k(TJobs jobs)
{
    const int b = blockIdx.x;
    int ji = 0;
    while (ji < 9 && b >= jobs.j[ji + 1].boffs) ++ji;
    TJob jb = jobs.j[ji];
    const int rel = b - jb.boffs;
    transpose_body(jb.in, jb.ld, jb.c0, jb.R, jb.out,
                   rel % jb.gbx, rel / jb.gbx, threadIdx.x);
}

// ---------------------------------------------------------------------------
// Merged converts (r8): [0,3072) features->bf16; [3072,3328) Wqkv v-slices.
// ---------------------------------------------------------------------------
__global__ __launch_bounds__(256) void conv_all_k(
    const float* __restrict__ features, ushort* __restrict__ featb,
    const float* __restrict__ wq0, const float* __restrict__ wq1,
    ushort* __restrict__ wv0, ushort* __restrict__ wv1)
{
    const int b = blockIdx.x;
    if (b < 3072) {
        const int i = b * 256 + threadIdx.x;          // < 786432
        const float4* p = reinterpret_cast<const float4*>(features) + 2 * (size_t)i;
        float4 a = p[0], c = p[1];
        uint4 o;
        o.x = f2bf(a.x) | ((unsigned)f2bf(a.y) << 16);
        o.y = f2bf(a.z) | ((unsigned)f2bf(a.w) << 16);
        o.z = f2bf(c.x) | ((unsigned)f2bf(c.y) << 16);
        o.w = f2bf(c.z) | ((unsigned)f2bf(c.w) << 16);
        reinterpret_cast<uint4*>(featb)[i] = o;
    } else {
        const int bb = b - 3072;
        const float* src = (bb >= 128) ? wq1 : wq0;
        ushort* dst = (bb >= 128) ? wv1 : wv0;
        const int idx = (bb & 127) * 256 + threadIdx.x;   // < 32768
        const int row = idx >> 6, c8 = (idx & 63) * 8;
        const float4* p = reinterpret_cast<const float4*>(
            src + (size_t)row * (3 * EDIM) + 2 * EDIM + c8);
        float4 a = p[0], c = p[1];
        uint4 o;
        o.x = f2bf(a.x) | ((unsigned)f2bf(a.y) << 16);
        o.y = f2bf(a.z) | ((unsigned)f2bf(a.w) << 16);
        o.z = f2bf(c.x) | ((unsigned)f2bf(c.y) << 16);
        o.w = f2bf(c.z) | ((unsigned)f2bf(c.w) << 16);
        *reinterpret_cast<uint4*>(dst + (size_t)row * EDIM + c8) = o;
    }
}

// ---------------------------------------------------------------------------
// G projection + embedded targets counting sort (r8, grid (128,9)).
// ---------------------------------------------------------------------------
__global__ __launch_bounds__(256) void gproj_k(
    const float* __restrict__ Wf, const float* __restrict__ bfv,
    const float* __restrict__ emb, ushort* __restrict__ BTg,
    float* __restrict__ C0s, const int* __restrict__ targets,
    int* __restrict__ perm, int* __restrict__ boff)
{
    if (blockIdx.y == 8) {
        if (blockIdx.x != 0) return;
        __shared__ int cnt[NTOK], off_s[NTOK], cur[NTOK];
        const int tid = threadIdx.x;
        if (tid < NTOK) cnt[tid] = 0;
        __syncthreads();
        for (int i = tid; i < BTOT; i += 256) atomicAdd(&cnt[targets[i]], 1);
        __syncthreads();
        if (tid == 0) {
            int s = 0;
            for (int b = 0; b < NTOK; ++b) { off_s[b] = s; cur[b] = s; s += cnt[b]; }
            for (int b = 0; b < NTOK; ++b) boff[b] = off_s[b];
            boff[NTOK] = s;
        }
        __syncthreads();
        for (int i = tid; i < BTOT; i += 256) {
            int t = targets[i];
            int p = atomicAdd(&cur[t], 1);
            perm[p] = i;
        }
        return;
    }

    const int hm = blockIdx.x;           // h*16 + m
    const int h = hm >> 4, m = hm & 15;
    const int l = threadIdx.x & 63, w = threadIdx.x >> 6;
    const int t = l & 15, isub = l >> 4;
    const int colb = m * 512 + h * 64;
    const int ibase = blockIdx.y * (INP / 8);

    float4 e[16];
#pragma unroll
    for (int q = 0; q < 16; ++q)
        e[q] = *reinterpret_cast<const float4*>(emb + t * EDIM + h * 64 + q * 4);

    const int n = t * 128 + hm;
    for (int i0 = ibase; i0 < ibase + INP / 8; i0 += 16) {
        const int i = i0 + w * 4 + isub;
        const float* wr = Wf + (size_t)i * KVW + colb;
        float acc = 0.f;
#pragma unroll
        for (int q = 0; q < 16; ++q) {
            float4 v4 = *reinterpret_cast<const float4*>(wr + q * 4);
            acc = fmaf(v4.x, e[q].x, fmaf(v4.y, e[q].y,
                  fmaf(v4.z, e[q].z, fmaf(v4.w, e[q].w, acc))));
        }
        BTg[(size_t)n * INP + i] = f2bf(acc);
    }
    if (blockIdx.y == 0 && w == 0 && isub == 0) {
        const float* br = bfv + colb;
        float acc = 0.f;
#pragma unroll
        for (int q = 0; q < 16; ++q) {
            float4 v4 = *reinterpret_cast<const float4*>(br + q * 4);
            acc = fmaf(v4.x, e[q].x, fmaf(v4.y, e[q].y,
                  fmaf(v4.z, e[q].z, fmaf(v4.w, e[q].w, acc))));
        }
        C0s[n] = 0.125f * acc;
    }
}

// ---------------------------------------------------------------------------
// Old 2-barrier MFMA GEMM (m97 structure) — kept for Wcomb (tiny grids).
// ---------------------------------------------------------------------------
template <int BM, int BN, int WM, int WN, int NW, bool GELU, bool OUTBF>
__global__ __launch_bounds__(NW * 64) void gemm_mfma_k(
    const ushort* __restrict__ A, int lda,
    const ushort* __restrict__ BT, int ldb,
    void* __restrict__ Cp, int ldc, int K,
    const float* __restrict__ bias,
    const ushort* __restrict__ res, int ldr,
    float scale)
{
    static_assert((BM / WM) * (BN / WN) == NW, "wave grid");
    static_assert(BM % (NW * 8) == 0 && BN % (NW * 8) == 0, "staging");
    constexpr int FM = WM / 16, FN = WN / 16;
    constexpr int IA = BM * 8 / (NW * 64), IB = BN * 8 / (NW * 64);
    constexpr int RA = BM / NW, RB = BN / NW;

    __shared__ bf16x8 As[BM][8];
    __shared__ bf16x8 Bs[BN][8];
    const int tid = threadIdx.x;
    const int l   = tid & 63;
    const int w   = tid >> 6;
    const int wm  = w / (BN / WN), wn = w % (BN / WN);
    const int brow = blockIdx.y * BM, bcol = blockIdx.x * BN;

    const int lr = l >> 3;
    const int ls = (l & 7) ^ lr;
    const ushort* Ab = A  + (size_t)(brow + w * RA + lr) * lda + ls * 8;
    const ushort* Bb = BT + (size_t)(bcol + w * RB + lr) * ldb + ls * 8;

    f32x4 acc[FM][FN];
#pragma unroll
    for (int i = 0; i < FM; ++i)
#pragma unroll
        for (int j = 0; j < FN; ++j) acc[i][j] = (f32x4)0.f;

    for (int k0 = 0; k0 < K; k0 += 64) {
#pragma unroll
        for (int i = 0; i < IA; ++i)
            __builtin_amdgcn_global_load_lds(
                (const __attribute__((address_space(1))) void*)(Ab + (size_t)(i * 8) * lda + k0),
                (__attribute__((address_space(3))) void*)&As[w * RA + i * 8][0],
                16, 0, 0);
#pragma unroll
        for (int i = 0; i < IB; ++i)
            __builtin_amdgcn_global_load_lds(
                (const __attribute__((address_space(1))) void*)(Bb + (size_t)(i * 8) * ldb + k0),
                (__attribute__((address_space(3))) void*)&Bs[w * RB + i * 8][0],
                16, 0, 0);
        __syncthreads();
#pragma unroll
        for (int kh = 0; kh < 2; ++kh) {
            const int slot = (kh * 4 + (l >> 4)) ^ (l & 7);
            bf16x8 af[FM], bfr[FN];
#pragma unroll
            for (int mt = 0; mt < FM; ++mt)
                af[mt] = As[wm * WM + mt * 16 + (l & 15)][slot];
#pragma unroll
            for (int nt = 0; nt < FN; ++nt)
                bfr[nt] = Bs[wn * WN + nt * 16 + (l & 15)][slot];
#pragma unroll
            for (int mt = 0; mt < FM; ++mt)
#pragma unroll
                for (int nt = 0; nt < FN; ++nt)
                    acc[mt][nt] = __builtin_amdgcn_mfma_f32_16x16x32_bf16(
                        af[mt], bfr[nt], acc[mt][nt], 0, 0, 0);
        }
        __syncthreads();
    }

    const int cr = (l >> 4) * 4, cc = l & 15;
#pragma unroll
    for (int mt = 0; mt < FM; ++mt) {
#pragma unroll
        for (int nt = 0; nt < FN; ++nt) {
            const int gc = bcol + wn * WN + nt * 16 + cc;
            const float bv = bias ? bias[gc] : 0.f;
#pragma unroll
            for (int r = 0; r < 4; ++r) {
                const size_t gr = (size_t)brow + wm * WM + mt * 16 + cr + r;
                float v = acc[mt][nt][r] * scale + bv;
                if (GELU) v = 0.5f * v * (1.f + erff(v * 0.70710678118654752f));
                if (res) v += bf2f(res[gr * ldr + gc]);
                if (OUTBF) ((ushort*)Cp)[gr * ldc + gc] = f2bf(v);
                else       ((float*)Cp)[gr * ldc + gc]  = v;
            }
        }
    }
}

// ---------------------------------------------------------------------------
// NEW: 128x128 barrier-minimal pipelined GEMM for the layer stack — same
// proven schedule as gemm_v256_k (dbuf, staging->inactive buffer, frag
// ds_reads pre-issued, one __syncthreads per K-tile whose vmcnt(0) drain
// fences staging), shrunk to 4 waves / 2 phases. K-order + epilogue math
// identical to gemm_mfma_k -> bit-identical output.
// ---------------------------------------------------------------------------
template <bool GELU, bool OUTBF>
__global__ __launch_bounds__(256, 2) void gemm_pipe_k(
    const ushort* __restrict__ A, int lda,
    const ushort* __restrict__ BT, int ldb,
    void* __restrict__ Cp, int ldc, int K,
    const float* __restrict__ bias,
    const ushort* __restrict__ res, int ldr,
    float scale)
{
    __shared__ bf16x8 Asl[2][128][8];
    __shared__ bf16x8 Bsl[2][128][8];
    const int tid = threadIdx.x;
    const int l = tid & 63, w = tid >> 6;
    const int wm = w >> 1, wn = w & 1;      // 2 x 2 wave grid, 64x64 each
    const int brow = blockIdx.y * 128, bcol = blockIdx.x * 128;
    const int lr = l >> 3, ls = (l & 7) ^ lr;

    const ushort* Ab = A  + (size_t)(brow + w * 32 + lr) * lda + ls * 8;
    const ushort* Bb = BT + (size_t)(bcol + w * 32 + lr) * ldb + ls * 8;

#define STAGE_P(d, t) do { const int k0s = (t) * 64;                          \
    _Pragma("unroll")                                                          \
    for (int g = 0; g < 4; ++g)                                                \
        __builtin_amdgcn_global_load_lds(                                      \
            (const __attribute__((address_space(1))) void*)(Ab + (size_t)(g * 8) * lda + k0s), \
            (__attribute__((address_space(3))) void*)&Asl[d][w * 32 + g * 8][0], 16, 0, 0);    \
    _Pragma("unroll")                                                          \
    for (int g = 0; g < 4; ++g)                                                \
        __builtin_amdgcn_global_load_lds(                                      \
            (const __attribute__((address_space(1))) void*)(Bb + (size_t)(g * 8) * ldb + k0s), \
            (__attribute__((address_space(3))) void*)&Bsl[d][w * 32 + g * 8][0], 16, 0, 0);    \
} while (0)

#define RD_AP(dst, dd, kh) do {                                                \
    const int slot_ = ((kh) * 4 + (l >> 4)) ^ (l & 7);                         \
    _Pragma("unroll")                                                          \
    for (int mt = 0; mt < 4; ++mt)                                             \
        dst[mt] = Asl[dd][wm * 64 + mt * 16 + (l & 15)][slot_];                \
} while (0)

#define RD_BP(dd, kh) do {                                                     \
    const int slot_ = ((kh) * 4 + (l >> 4)) ^ (l & 7);                         \
    _Pragma("unroll")                                                          \
    for (int nt = 0; nt < 4; ++nt)                                             \
        bfr[nt][kh] = Bsl[dd][wn * 64 + nt * 16 + (l & 15)][slot_];            \
} while (0)

#define MFMA_P(af, kh) do {                                                    \
    __builtin_amdgcn_s_setprio(1);                                             \
    _Pragma("unroll")                                                          \
    for (int mt = 0; mt < 4; ++mt)                                             \
        _Pragma("unroll")                                                      \
        for (int nt = 0; nt < 4; ++nt)                                         \
            acc[mt][nt] = __builtin_amdgcn_mfma_f32_16x16x32_bf16(             \
                af[mt], bfr[nt][kh], acc[mt][nt], 0, 0, 0);                    \
    __builtin_amdgcn_s_setprio(0);                                             \
} while (0)

    f32x4 acc[4][4];
#pragma unroll
    for (int i = 0; i < 4; ++i)
#pragma unroll
        for (int j = 0; j < 4; ++j) acc[i][j] = (f32x4)0.f;

    STAGE_P(0, 0);
    STAGE_P(1, 1);
    asm volatile("s_waitcnt vmcnt(8)" ::: "memory");
    __builtin_amdgcn_s_barrier();

    bf16x8 aA[4], aB[4], bfr[4][2];
    RD_AP(aA, 0, 0);
    RD_BP(0, 0);

    const int NT = K / 64;
    for (int j = 0; j < NT; ++j) {
        const int d = j & 1;
        if (j > 0 && j + 1 < NT) STAGE_P(d ^ 1, j + 1);
        RD_AP(aB, d, 1);
        RD_BP(d, 1);
        MFMA_P(aA, 0);
        MFMA_P(aB, 1);
        __syncthreads();            // vmcnt(0)+lgkmcnt(0) drain: tile j+1
                                    // staged, all waves done with buffer d
        if (j + 1 < NT) {
            RD_AP(aA, d ^ 1, 0);
            RD_BP(d ^ 1, 0);
        }
    }
#undef STAGE_P
#undef RD_AP
#undef RD_BP
#undef MFMA_P

    const int cr = (l >> 4) * 4, cc = l & 15;
#pragma unroll
    for (int mt = 0; mt < 4; ++mt) {
#pragma unroll
        for (int nt = 0; nt < 4; ++nt) {
            const int gc = bcol + wn * 64 + nt * 16 + cc;
            const float bv = bias ? bias[gc] : 0.f;
#pragma unroll
            for (int r = 0; r < 4; ++r) {
                const size_t gr = (size_t)brow + wm * 64 + mt * 16 + cr + r;
                float v = acc[mt][nt][r] * scale + bv;
                if (GELU) v = 0.5f * v * (1.f + erff(v * 0.70710678118654752f));
                if (res) v += bf2f(res[gr * ldr + gc]);
                if (OUTBF) ((ushort*)Cp)[gr * ldc + gc] = f2bf(v);
                else       ((float*)Cp)[gr * ldc + gc]  = v;
            }
        }
    }
}

// ---------------------------------------------------------------------------
// 256x256 v-GEMM, barrier-minimal pipeline, plain 2-D grid (r13, proven).
// ---------------------------------------------------------------------------
__global__ __launch_bounds__(512, 2) void gemm_v256_k(
    const ushort* __restrict__ A,        // featb [BTOT][INP]
    const ushort* __restrict__ BT,       // WfvT [ENW][INP]
    const float* __restrict__ bias,      // bfv + ENW
    ushort* __restrict__ C)              // vb [BTOT][ENW]
{
    __shared__ bf16x8 lds[2][2][256][8];   // [dbuf][A/B][row][16B chunk]
    const int tid = threadIdx.x;
    const int l = tid & 63, w = tid >> 6;
    const int wm = w >> 2, wn = w & 3;      // 2 x 4 wave grid
    const int brow = blockIdx.y * 256, bcol = blockIdx.x * 256;
    const int lr = l >> 3, ls = (l & 7) ^ lr;

    const ushort* Ab = A  + (size_t)(brow + w * 8 + lr) * INP + ls * 8;
    const ushort* Bb = BT + (size_t)(bcol + w * 8 + lr) * INP + ls * 8;

#define STAGE_T(d, t) do { const int k0s = (t) * 64;                          \
    _Pragma("unroll")                                                          \
    for (int g = 0; g < 4; ++g)                                                \
        __builtin_amdgcn_global_load_lds(                                      \
            (const __attribute__((address_space(1))) void*)(Ab + (size_t)(g * 64) * INP + k0s), \
            (__attribute__((address_space(3))) void*)&lds[d][0][g * 64 + w * 8][0], 16, 0, 0);  \
    _Pragma("unroll")                                                          \
    for (int g = 0; g < 4; ++g)                                                \
        __builtin_amdgcn_global_load_lds(                                      \
            (const __attribute__((address_space(1))) void*)(Bb + (size_t)(g * 64) * INP + k0s), \
            (__attribute__((address_space(3))) void*)&lds[d][1][g * 64 + w * 8][0], 16, 0, 0);  \
} while (0)

#define RD_A(dst, dd, rh, kh) do {                                             \
    const int slot_ = ((kh) * 4 + (l >> 4)) ^ (l & 7);                         \
    _Pragma("unroll")                                                          \
    for (int mt = 0; mt < 4; ++mt)                                             \
        dst[mt] = lds[dd][0][wm * 128 + (rh) * 64 + mt * 16 + (l & 15)][slot_]; \
} while (0)

#define RD_B(dd, kh) do {                                                      \
    const int slot_ = ((kh) * 4 + (l >> 4)) ^ (l & 7);                         \
    _Pragma("unroll")                                                          \
    for (int nt = 0; nt < 4; ++nt)                                             \
        bfr[nt][kh] = lds[dd][1][wn * 64 + nt * 16 + (l & 15)][slot_];         \
} while (0)

#define MFMA4(base, af, kh) do {                                               \
    __builtin_amdgcn_s_setprio(1);                                             \
    _Pragma("unroll")                                                          \
    for (int mt = 0; mt < 4; ++mt)                                             \
        _Pragma("unroll")                                                      \
        for (int nt = 0; nt < 4; ++nt)                                         \
            acc[(base) + mt][nt] = __builtin_amdgcn_mfma_f32_16x16x32_bf16(    \
                af[mt], bfr[nt][kh], acc[(base) + mt][nt], 0, 0, 0);           \
    __builtin_amdgcn_s_setprio(0);                                             \
} while (0)

    f32x4 acc[8][4];
#pragma unroll
    for (int i = 0; i < 8; ++i)
#pragma unroll
        for (int j = 0; j < 4; ++j) acc[i][j] = (f32x4)0.f;

    // prologue: tiles 0 and 1 in flight; wait tile 0 only.
    STAGE_T(0, 0);
    STAGE_T(1, 1);
    asm volatile("s_waitcnt vmcnt(8)" ::: "memory");
    __builtin_amdgcn_s_barrier();

    bf16x8 aA[4], aB[4], bfr[4][2];
    RD_A(aA, 0, 0, 0);
    RD_B(0, 0);

    const int NT = INP / 64;   // 24
    for (int j = 0; j < NT; ++j) {
        const int d = j & 1;
        if (j > 0 && j + 1 < NT) STAGE_T(d ^ 1, j + 1);
        RD_A(aB, d, 0, 1);          // phase-1 frags
        RD_B(d, 1);
        MFMA4(0, aA, 0);            // phase 0 (rh0,kh0)
        RD_A(aA, d, 1, 0);          // phase-2 frags
        MFMA4(0, aB, 1);            // phase 1 (rh0,kh1)
        RD_A(aB, d, 1, 1);          // phase-3 frags
        MFMA4(4, aA, 0);            // phase 2 (rh1,kh0)
        MFMA4(4, aB, 1);            // phase 3 (rh1,kh1)
        __syncthreads();            // drains vmcnt(0): tile j+1 staged + all
                                    // waves done reading buffer d
        if (j + 1 < NT) {           // pre-issue next tile's phase-0 frags
            RD_A(aA, d ^ 1, 0, 0);
            RD_B(d ^ 1, 0);
        }
    }
#undef STAGE_T
#undef RD_A
#undef RD_B
#undef MFMA4

    const int cr = (l >> 4) * 4, cc = l & 15;
#pragma unroll
    for (int h = 0; h < 2; ++h)
#pragma unroll
        for (int mt = 0; mt < 4; ++mt)
#pragma unroll
            for (int nt = 0; nt < 4; ++nt) {
                const int gc = bcol + wn * 64 + nt * 16 + cc;
                const float bv = bias[gc];
#pragma unroll
                for (int r = 0; r < 4; ++r) {
                    const size_t gr = (size_t)brow + wm * 128 + h * 64 + mt * 16 + cr + r;
                    C[gr * ENW + gc] = f2bf(acc[h * 4 + mt][nt][r] + bv);
                }
            }
}

// ---------------------------------------------------------------------------
// Bucketed dots GEMM + in-epilogue log-softmax (proven).
// ---------------------------------------------------------------------------
__global__ __launch_bounds__(256) void gemm_dots_k(
    const ushort* __restrict__ A,
    const ushort* __restrict__ BT,
    const int* __restrict__ perm, const int* __restrict__ boff,
    const float* __restrict__ C0s, float* __restrict__ Csel)
{
    const int bucket = blockIdx.y;
    const int off = boff[bucket], end = boff[bucket + 1];
    const int tile = blockIdx.x;
    if (tile * 128 >= end - off) return;

    __shared__ bf16x8 As[128][8];
    __shared__ bf16x8 Bs[128][8];
    const int tid = threadIdx.x;
    const int l = tid & 63, w = tid >> 6;
    const int wm = w >> 1, wn = w & 1;
    const int lr = l >> 3;
    const int ls = (l & 7) ^ lr;

    int rowidx[4];
#pragma unroll
    for (int i = 0; i < 4; ++i) {
        int rg = off + tile * 128 + w * 32 + lr + i * 8;
        rowidx[i] = perm[rg < end ? rg : off];
    }
    const ushort* Bb = BT + (size_t)(bucket * 128 + w * 32 + lr) * INP + ls * 8;

    f32x4 acc[4][4];
#pragma unroll
    for (int i = 0; i < 4; ++i)
#pragma unroll
        for (int j = 0; j < 4; ++j) acc[i][j] = (f32x4)0.f;

    for (int k0 = 0; k0 < INP; k0 += 64) {
#pragma unroll
        for (int i = 0; i < 4; ++i)
            __builtin_amdgcn_global_load_lds(
                (const __attribute__((address_space(1))) void*)(
                    A + (size_t)rowidx[i] * INP + ls * 8 + k0),
                (__attribute__((address_space(3))) void*)&As[w * 32 + i * 8][0],
                16, 0, 0);
#pragma unroll
        for (int i = 0; i < 4; ++i)
            __builtin_amdgcn_global_load_lds(
                (const __attribute__((address_space(1))) void*)(
                    Bb + (size_t)(i * 8) * INP + k0),
                (__attribute__((address_space(3))) void*)&Bs[w * 32 + i * 8][0],
                16, 0, 0);
        __syncthreads();
#pragma unroll
        for (int kh = 0; kh < 2; ++kh) {
            const int slot = (kh * 4 + (l >> 4)) ^ (l & 7);
            bf16x8 af[4], bfr[4];
#pragma unroll
            for (int mt = 0; mt < 4; ++mt)
                af[mt] = As[wm * 64 + mt * 16 + (l & 15)][slot];
#pragma unroll
            for (int nt = 0; nt < 4; ++nt)
                bfr[nt] = Bs[wn * 64 + nt * 16 + (l & 15)][slot];
#pragma unroll
            for (int mt = 0; mt < 4; ++mt)
#pragma unroll
                for (int nt = 0; nt < 4; ++nt)
                    acc[mt][nt] = __builtin_amdgcn_mfma_f32_16x16x32_bf16(
                        af[mt], bfr[nt], acc[mt][nt], 0, 0, 0);
        }
        __syncthreads();
    }

    const int cr = (l >> 4) * 4, cc = l & 15;
#pragma unroll
    for (int mt = 0; mt < 4; ++mt) {
#pragma unroll
        for (int nt = 0; nt < 4; ++nt) {
            const int gc = wn * 64 + nt * 16 + cc;
            const float bv = C0s[bucket * 128 + gc];
#pragma unroll
            for (int r = 0; r < 4; ++r) {
                float val = acc[mt][nt][r] * 0.125f + bv;
                float mx = val;
                mx = fmaxf(mx, __shfl_xor(mx, 1, 64));
                mx = fmaxf(mx, __shfl_xor(mx, 2, 64));
                mx = fmaxf(mx, __shfl_xor(mx, 4, 64));
                mx = fmaxf(mx, __shfl_xor(mx, 8, 64));
                float e = expf(val - mx);
                e += __shfl_xor(e, 1, 64);
                e += __shfl_xor(e, 2, 64);
                e += __shfl_xor(e, 4, 64);
                e += __shfl_xor(e, 8, 64);
                const float lse = mx + logf(e);
                int rg = off + tile * 128 + wm * 64 + mt * 16 + cr + r;
                int orow = perm[rg < end ? rg : off];
                Csel[(size_t)orow * 128 + gc] = val - lse;
            }
        }
    }
}

// ---------------------------------------------------------------------------
// Layer-0 attend: weights = dsel log-probs (precomputed), v bf16.
// ---------------------------------------------------------------------------
__global__ __launch_bounds__(512) void attend0_k(
    const float* __restrict__ dsel, const ushort* __restrict__ vb,
    ushort* __restrict__ o)
{
    const int bt = blockIdx.x;
    const int l  = threadIdx.x & 63;
    const int h  = threadIdx.x >> 6;
    const int dg = l & 7, mg = l >> 3;

    const float w0 = dsel[(size_t)bt * 128 + h * 16 + mg];
    const float w1 = dsel[(size_t)bt * 128 + h * 16 + 8 + mg];

    const ushort* base = vb + (size_t)bt * ENW + h * 64 + dg * 8;
    uint4 v0 = *reinterpret_cast<const uint4*>(base + (size_t)mg * EDIM);
    uint4 v1 = *reinterpret_cast<const uint4*>(base + (size_t)(8 + mg) * EDIM);
    const ushort* u0 = reinterpret_cast<const ushort*>(&v0);
    const ushort* u1 = reinterpret_cast<const ushort*>(&v1);
    float acc[8];
#pragma unroll
    for (int j = 0; j < 8; ++j)
        acc[j] = w0 * bf2f(u0[j]) + w1 * bf2f(u1[j]);
#pragma unroll
    for (int off = 8; off < 64; off <<= 1)
#pragma unroll
        for (int j = 0; j < 8; ++j) acc[j] += __shfl_xor(acc[j], off, 64);

    if (mg == 0) {
        uint4 pk;
        pk.x = f2bf(acc[0]) | ((unsigned)f2bf(acc[1]) << 16);
        pk.y = f2bf(acc[2]) | ((unsigned)f2bf(acc[3]) << 16);
        pk.z = f2bf(acc[4]) | ((unsigned)f2bf(acc[5]) << 16);
        pk.w = f2bf(acc[6]) | ((unsigned)f2bf(acc[7]) << 16);
        *reinterpret_cast<uint4*>(o + (size_t)bt * EDIM + h * 64 + dg * 8) = pk;
    }
}

// ---------------------------------------------------------------------------
// Row LayerNorm over E=512: one wave per row; emits bf16 ONLY (r14).
// ---------------------------------------------------------------------------
__global__ __launch_bounds__(256) void ln_k(
    const float* __restrict__ x, const float* __restrict__ g,
    const float* __restrict__ b, ushort* __restrict__ yb)
{
    const int row = blockIdx.x * 4 + (threadIdx.x >> 6);
    const int lane = threadIdx.x & 63;
    const float* xr = x + (size_t)row * EDIM + lane * 8;
    float4 a0 = *reinterpret_cast<const float4*>(xr);
    float4 a1 = *reinterpret_cast<const float4*>(xr + 4);
    float v[8] = {a0.x, a0.y, a0.z, a0.w, a1.x, a1.y, a1.z, a1.w};

    float s = 0.f;
#pragma unroll
    for (int j = 0; j < 8; ++j) s += v[j];
#pragma unroll
    for (int off = 32; off; off >>= 1) s += __shfl_xor(s, off, 64);
    const float m = s * (1.f / 512.f);

    float q = 0.f;
#pragma unroll
    for (int j = 0; j < 8; ++j) { float d = v[j] - m; q = fmaf(d, d, q); }
#pragma unroll
    for (int off = 32; off; off >>= 1) q += __shfl_xor(q, off, 64);
    const float inv = rsqrtf(q * (1.f / 512.f) + 1e-5f);

    const int c = lane * 8;
    float4 g0 = *reinterpret_cast<const float4*>(g + c);
    float4 g1 = *reinterpret_cast<const float4*>(g + c + 4);
    float4 b0 = *reinterpret_cast<const float4*>(b + c);
    float4 b1 = *reinterpret_cast<const float4*>(b + c + 4);
    float gg[8] = {g0.x, g0.y, g0.z, g0.w, g1.x, g1.y, g1.z, g1.w};
    float bb[8] = {b0.x, b0.y, b0.z, b0.w, b1.x, b1.y, b1.z, b1.w};
    float out[8];
#pragma unroll
    for (int j = 0; j < 8; ++j) out[j] = (v[j] - m) * inv * gg[j] + bb[j];
    uint4 p;
    p.x = f2bf(out[0]) | ((unsigned)f2bf(out[1]) << 16);
    p.y = f2bf(out[2]) | ((unsigned)f2bf(out[3]) << 16);
    p.z = f2bf(out[4]) | ((unsigned)f2bf(out[5]) << 16);
    p.w = f2bf(out[6]) | ((unsigned)f2bf(out[7]) << 16);
    *reinterpret_cast<uint4*>(yb + (size_t)row * EDIM + c) = p;
}

// out[row] = x[row,:] . Wm + bm
__global__ __launch_bounds__(256) void final_k(
    const float* __restrict__ x, const float* __restrict__ Wm,
    const float* __restrict__ bm, float* __restrict__ out)
{
    const int row = blockIdx.x * 4 + (threadIdx.x >> 6);
    const int lane = threadIdx.x & 63;
    const float* xr = x + (size_t)row * EDIM + lane * 8;
    const float* wr = Wm + lane * 8;
    float s = 0.f;
#pragma unroll
    for (int j = 0; j < 8; ++j) s = fmaf(xr[j], wr[j], s);
#pragma unroll
    for (int off = 32; off; off >>= 1) s += __shfl_xor(s, off, 64);
    if (lane == 0) out[row] = s + bm[0];
}

// ---------------------------------------------------------------------------
extern "C" void kernel_launch(void* const* d_in, const int* in_sizes, int n_in,
                              void* d_out, int out_size, void* d_ws, size_t ws_size,
                              hipStream_t stream)
{
    (void)in_sizes; (void)n_in; (void)out_size; (void)ws_size;
    const float* features = (const float*)d_in[0];
    const int*   targets  = (const int*)d_in[1];
    const float* emb      = (const float*)d_in[2];
    const float* Wf       = (const float*)d_in[3];
    const float* bfv      = (const float*)d_in[4];
    const float* a0Wo     = (const float*)d_in[5];
    const float* a0bo     = (const float*)d_in[6];
    const float* Wm       = (const float*)d_in[7];
    const float* bm       = (const float*)d_in[8];
    const float *ffg[3], *ffb[3], *W1[3], *b1[3], *W2[3], *b2[3];
    for (int i = 0; i < 3; ++i) {
        ffg[i] = (const float*)d_in[9 + 6 * i];
        ffb[i] = (const float*)d_in[10 + 6 * i];
        W1[i]  = (const float*)d_in[11 + 6 * i];
        b1[i]  = (const float*)d_in[12 + 6 * i];
        W2[i]  = (const float*)d_in[13 + 6 * i];
        b2[i]  = (const float*)d_in[14 + 6 * i];
    }
    const float *ag[2], *abp[2], *aWqkv[2], *aWo[2], *abo[2];
    for (int i = 0; i < 2; ++i) {
        ag[i]    = (const float*)d_in[27 + 5 * i];
        abp[i]   = (const float*)d_in[28 + 5 * i];
        aWqkv[i] = (const float*)d_in[29 + 5 * i];
        aWo[i]   = (const float*)d_in[30 + 5 * i];
        abo[i]   = (const float*)d_in[31 + 5 * i];
    }

    // ---- workspace carve-up ----
    char* wsc = (char*)d_ws;
    auto alloc = [&](size_t bytes) { char* p = wsc; wsc += bytes; return p; };
    ushort* WfvT  = (ushort*)alloc((size_t)ENW * INP * 2);       // 25.2 MB
    ushort* BTg   = (ushort*)alloc((size_t)NDOT * INP * 2);      // 6.3 MB
    float*  C0s   = (float*) alloc((size_t)NDOT * 4);
    float*  dsel  = (float*) alloc((size_t)BTOT * 128 * 4);      // 2.1 MB
    int*    perm  = (int*)   alloc((size_t)BTOT * 4);
    int*    boff  = (int*)   alloc(32 * 4);
    ushort* a0WoT = (ushort*)alloc((size_t)EDIM * EDIM * 2);
    ushort *W1T[3], *W2T[3], *WoT[2], *Wv_bf[2], *WcombT[2];
    for (int i = 0; i < 3; ++i) {
        W1T[i] = (ushort*)alloc((size_t)FFH * EDIM * 2);
        W2T[i] = (ushort*)alloc((size_t)EDIM * FFH * 2);
    }
    for (int i = 0; i < 2; ++i) {
        WoT[i]    = (ushort*)alloc((size_t)EDIM * EDIM * 2);
        Wv_bf[i]  = (ushort*)alloc((size_t)EDIM * EDIM * 2);
        WcombT[i] = (ushort*)alloc((size_t)EDIM * EDIM * 2);
    }
    ushort* featb = (ushort*)alloc((size_t)BTOT * INP * 2);      // 12.6 MB
    ushort* o_b   = (ushort*)alloc((size_t)BTOT * EDIM * 2);     // 4.2 MB
    float*  x     = (float*) alloc((size_t)BTOT * EDIM * 4);     // 8.4 MB
    ushort* xlnb  = (ushort*)alloc((size_t)BTOT * EDIM * 2);
    ushort* hb    = (ushort*)alloc((size_t)BTOT * FFH * 2);      // 8.4 MB
    ushort* vb    = (ushort*)alloc((size_t)BTOT * ENW * 2);      // 67 MB

    const dim3 blk(256, 1, 1);

    // ---- prep: 3 separate dispatches (r8 structure — measured faster) ----
    conv_all_k<<<3328, blk, 0, stream>>>(features, featb,
                                         aWqkv[0], aWqkv[1], Wv_bf[0], Wv_bf[1]);
    gproj_k<<<dim3(128, 9), blk, 0, stream>>>(Wf, bfv, emb, BTg, C0s,
                                              targets, perm, boff);

    TJobs tj;
    int ob = 0, ji = 0;
    auto addj = [&](const float* in, ushort* out, int ld, int c0, int R,
                    int gbx, int gby) {
        tj.j[ji++] = {in, out, ld, c0, R, gbx, ob};
        ob += gbx * gby;
    };
    addj(Wf, WfvT, KVW, ENW, INP, 128, 24);       // v-half of Wf (3072 blocks)
    addj(a0Wo, a0WoT, EDIM, 0, EDIM, 8, 8);
    for (int i = 0; i < 3; ++i) {
        addj(W1[i], W1T[i], FFH, 0, EDIM, 16, 8);
        addj(W2[i], W2T[i], EDIM, 0, FFH, 8, 16);
    }
    addj(aWo[0], WoT[0], EDIM, 0, EDIM, 8, 8);
    addj(aWo[1], WoT[1], EDIM, 0, EDIM, 8, 8);
    transpose_all_k<<<ob, blk, 0, stream>>>(tj);

    // ---- layer 0 ----
    const float CATT = -44.36141955583650f;   // -16*ln(16)
    gemm_dots_k<<<dim3(32, 16), blk, 0, stream>>>(featb, BTg, perm, boff,
                                                  C0s, dsel);
    for (int i = 0; i < 2; ++i)
        gemm_mfma_k<64, 128, 32, 64, 4, false, true>
            <<<dim3(EDIM / 128, EDIM / 64), blk, 0, stream>>>(
            WoT[i], EDIM, Wv_bf[i], EDIM, WcombT[i], EDIM, EDIM,
            nullptr, nullptr, 0, CATT);
    gemm_v256_k<<<dim3(ENW / 256, BTOT / 256), dim3(512, 1, 1), 0, stream>>>(
        featb, WfvT, bfv + ENW, vb);
    attend0_k<<<BTOT, 512, 0, stream>>>(dsel, vb, o_b);
    gemm_pipe_k<false, false>
        <<<dim3(EDIM / 128, BTOT / 128), blk, 0, stream>>>(
        o_b, EDIM, a0WoT, EDIM, x, EDIM, EDIM, a0bo, nullptr, 0, 1.f);

    auto ln = [&](const float* g, const float* b) {
        ln_k<<<BTOT / 4, blk, 0, stream>>>(x, g, b, xlnb);
    };
    auto ff = [&](int i) {
        ln(ffg[i], ffb[i]);
        gemm_pipe_k<true, true>
            <<<dim3(FFH / 128, BTOT / 128), blk, 0, stream>>>(
            xlnb, EDIM, W1T[i], EDIM, hb, FFH, EDIM, b1[i], nullptr, 0, 1.f);
        gemm_pipe_k<false, false>
            <<<dim3(EDIM / 128, BTOT / 128), blk, 0, stream>>>(
            hb, FFH, W2T[i], FFH, x, EDIM, FFH, b2[i], xlnb, EDIM, 1.f);
    };
    auto attn = [&](int i) {
        ln(ag[i], abp[i]);
        gemm_pipe_k<false, false>
            <<<dim3(EDIM / 128, BTOT / 128), blk, 0, stream>>>(
            xlnb, EDIM, WcombT[i], EDIM, x, EDIM, EDIM, abo[i], xlnb, EDIM, 1.f);
    };

    ff(0);
    attn(0);
    ff(1);
    attn(1);
    ff(2);

    final_k<<<BTOT / 4, blk, 0, stream>>>(x, Wm, bm, (float*)d_out);
}

// Round 16
// 434.725 us; speedup vs baseline: 1.1557x; 1.1557x over previous
//
#include <hip/hip_runtime.h>
#include <math.h>

// MixedHead: B=16,T=256 -> BT=4096; INP=1536; E=512; H=8; N=16; D=64.
#define BTOT 4096
#define INP  1536
#define EDIM 512
#define NTOK 16
#define KVW  16384   // 2*E*N
#define ENW  8192    // E*N
#define FFH  1024    // 2*E
#define NDOT 2048    // 16 targets x 128 (h,m)

typedef __attribute__((ext_vector_type(8))) __bf16 bf16x8;
typedef __attribute__((ext_vector_type(4))) float f32x4;

__device__ __forceinline__ ushort f2bf(float f) {
    union { float f; unsigned u; } v; v.f = f;
    unsigned r = v.u + 0x7fffu + ((v.u >> 16) & 1u);
    return (ushort)(r >> 16);
}
__device__ __forceinline__ float bf2f(ushort h) {
    union { unsigned u; float f; } v; v.u = ((unsigned)h) << 16;
    return v.f;
}

// ---------------------------------------------------------------------------
// Transpose f32 [R][ld] (cols c0..) -> bf16 [C][R]. 10 jobs, one launch (r8).
// ---------------------------------------------------------------------------
__device__ __forceinline__ void transpose_body(
    const float* in, int ld, int c0, int R, ushort* out,
    int bx, int by, int tid)
{
    __shared__ float t[64][65];
    const int bc = bx * 64 + c0;
    const int br = by * 64;
#pragma unroll
    for (int it = 0; it < 16; ++it) {
        int idx = tid + it * 256;
        int r = idx >> 6, c = idx & 63;
        t[r][c] = in[(size_t)(br + r) * ld + bc + c];
    }
    __syncthreads();
    const int C0 = bx * 64;
#pragma unroll
    for (int it = 0; it < 4; ++it) {
        int idx = tid + it * 256;          // 1024 = 64 cols x 16 row-quads
        int cc = idx >> 4, rp = idx & 15;
        uint2 w2;
        w2.x = f2bf(t[4 * rp + 0][cc]) | ((unsigned)f2bf(t[4 * rp + 1][cc]) << 16);
        w2.y = f2bf(t[4 * rp + 2][cc]) | ((unsigned)f2bf(t[4 * rp + 3][cc]) << 16);
        *reinterpret_cast<uint2*>(out + (size_t)(C0 + cc) * R + br + 4 * rp) = w2;
    }
}

struct TJob { const float* in; ushort* out; int ld, c0, R, gbx, boffs; };
struct TJobs { TJob j[10]; };

__global__ __launch_bounds__(256) void transpose_all_k(TJobs jobs)
{
    const int b = blockIdx.x;
    int ji = 0;
    while (ji < 9 && b >= jobs.j[ji + 1].boffs) ++ji;
    TJob jb = jobs.j[ji];
    const int rel = b - jb.boffs;
    transpose_body(jb.in, jb.ld, jb.c0, jb.R, jb.out,
                   rel % jb.gbx, rel / jb.gbx, threadIdx.x);
}

// ---------------------------------------------------------------------------
// Merged converts (r8): [0,3072) features->bf16; [3072,3328) Wqkv v-slices.
// ---------------------------------------------------------------------------
__global__ __launch_bounds__(256) void conv_all_k(
    const float* __restrict__ features, ushort* __restrict__ featb,
    const float* __restrict__ wq0, const float* __restrict__ wq1,
    ushort* __restrict__ wv0, ushort* __restrict__ wv1)
{
    const int b = blockIdx.x;
    if (b < 3072) {
        const int i = b * 256 + threadIdx.x;          // < 786432
        const float4* p = reinterpret_cast<const float4*>(features) + 2 * (size_t)i;
        float4 a = p[0], c = p[1];
        uint4 o;
        o.x = f2bf(a.x) | ((unsigned)f2bf(a.y) << 16);
        o.y = f2bf(a.z) | ((unsigned)f2bf(a.w) << 16);
        o.z = f2bf(c.x) | ((unsigned)f2bf(c.y) << 16);
        o.w = f2bf(c.z) | ((unsigned)f2bf(c.w) << 16);
        reinterpret_cast<uint4*>(featb)[i] = o;
    } else {
        const int bb = b - 3072;
        const float* src = (bb >= 128) ? wq1 : wq0;
        ushort* dst = (bb >= 128) ? wv1 : wv0;
        const int idx = (bb & 127) * 256 + threadIdx.x;   // < 32768
        const int row = idx >> 6, c8 = (idx & 63) * 8;
        const float4* p = reinterpret_cast<const float4*>(
            src + (size_t)row * (3 * EDIM) + 2 * EDIM + c8);
        float4 a = p[0], c = p[1];
        uint4 o;
        o.x = f2bf(a.x) | ((unsigned)f2bf(a.y) << 16);
        o.y = f2bf(a.z) | ((unsigned)f2bf(a.w) << 16);
        o.z = f2bf(c.x) | ((unsigned)f2bf(c.y) << 16);
        o.w = f2bf(c.z) | ((unsigned)f2bf(c.w) << 16);
        *reinterpret_cast<uint4*>(dst + (size_t)row * EDIM + c8) = o;
    }
}

// ---------------------------------------------------------------------------
// G projection + embedded targets counting sort (r8, grid (128,9)).
// ---------------------------------------------------------------------------
__global__ __launch_bounds__(256) void gproj_k(
    const float* __restrict__ Wf, const float* __restrict__ bfv,
    const float* __restrict__ emb, ushort* __restrict__ BTg,
    float* __restrict__ C0s, const int* __restrict__ targets,
    int* __restrict__ perm, int* __restrict__ boff)
{
    if (blockIdx.y == 8) {
        if (blockIdx.x != 0) return;
        __shared__ int cnt[NTOK], off_s[NTOK], cur[NTOK];
        const int tid = threadIdx.x;
        if (tid < NTOK) cnt[tid] = 0;
        __syncthreads();
        for (int i = tid; i < BTOT; i += 256) atomicAdd(&cnt[targets[i]], 1);
        __syncthreads();
        if (tid == 0) {
            int s = 0;
            for (int b = 0; b < NTOK; ++b) { off_s[b] = s; cur[b] = s; s += cnt[b]; }
            for (int b = 0; b < NTOK; ++b) boff[b] = off_s[b];
            boff[NTOK] = s;
        }
        __syncthreads();
        for (int i = tid; i < BTOT; i += 256) {
            int t = targets[i];
            int p = atomicAdd(&cur[t], 1);
            perm[p] = i;
        }
        return;
    }

    const int hm = blockIdx.x;           // h*16 + m
    const int h = hm >> 4, m = hm & 15;
    const int l = threadIdx.x & 63, w = threadIdx.x >> 6;
    const int t = l & 15, isub = l >> 4;
    const int colb = m * 512 + h * 64;
    const int ibase = blockIdx.y * (INP / 8);

    float4 e[16];
#pragma unroll
    for (int q = 0; q < 16; ++q)
        e[q] = *reinterpret_cast<const float4*>(emb + t * EDIM + h * 64 + q * 4);

    const int n = t * 128 + hm;
    for (int i0 = ibase; i0 < ibase + INP / 8; i0 += 16) {
        const int i = i0 + w * 4 + isub;
        const float* wr = Wf + (size_t)i * KVW + colb;
        float acc = 0.f;
#pragma unroll
        for (int q = 0; q < 16; ++q) {
            float4 v4 = *reinterpret_cast<const float4*>(wr + q * 4);
            acc = fmaf(v4.x, e[q].x, fmaf(v4.y, e[q].y,
                  fmaf(v4.z, e[q].z, fmaf(v4.w, e[q].w, acc))));
        }
        BTg[(size_t)n * INP + i] = f2bf(acc);
    }
    if (blockIdx.y == 0 && w == 0 && isub == 0) {
        const float* br = bfv + colb;
        float acc = 0.f;
#pragma unroll
        for (int q = 0; q < 16; ++q) {
            float4 v4 = *reinterpret_cast<const float4*>(br + q * 4);
            acc = fmaf(v4.x, e[q].x, fmaf(v4.y, e[q].y,
                  fmaf(v4.z, e[q].z, fmaf(v4.w, e[q].w, acc))));
        }
        C0s[n] = 0.125f * acc;
    }
}

// ---------------------------------------------------------------------------
// bf16 MFMA GEMM template (m97 structure, proven) — small GEMMs.
// res is bf16 (the LN output xlnb) — halves residual-read traffic (r14).
// ---------------------------------------------------------------------------
template <int BM, int BN, int WM, int WN, int NW, bool GELU, bool OUTBF>
__global__ __launch_bounds__(NW * 64) void gemm_mfma_k(
    const ushort* __restrict__ A, int lda,
    const ushort* __restrict__ BT, int ldb,
    void* __restrict__ Cp, int ldc, int K,
    const float* __restrict__ bias,
    const ushort* __restrict__ res, int ldr,
    float scale)
{
    static_assert((BM / WM) * (BN / WN) == NW, "wave grid");
    static_assert(BM % (NW * 8) == 0 && BN % (NW * 8) == 0, "staging");
    constexpr int FM = WM / 16, FN = WN / 16;
    constexpr int IA = BM * 8 / (NW * 64), IB = BN * 8 / (NW * 64);
    constexpr int RA = BM / NW, RB = BN / NW;

    __shared__ bf16x8 As[BM][8];
    __shared__ bf16x8 Bs[BN][8];
    const int tid = threadIdx.x;
    const int l   = tid & 63;
    const int w   = tid >> 6;
    const int wm  = w / (BN / WN), wn = w % (BN / WN);
    const int brow = blockIdx.y * BM, bcol = blockIdx.x * BN;

    const int lr = l >> 3;
    const int ls = (l & 7) ^ lr;
    const ushort* Ab = A  + (size_t)(brow + w * RA + lr) * lda + ls * 8;
    const ushort* Bb = BT + (size_t)(bcol + w * RB + lr) * ldb + ls * 8;

    f32x4 acc[FM][FN];
#pragma unroll
    for (int i = 0; i < FM; ++i)
#pragma unroll
        for (int j = 0; j < FN; ++j) acc[i][j] = (f32x4)0.f;

    for (int k0 = 0; k0 < K; k0 += 64) {
#pragma unroll
        for (int i = 0; i < IA; ++i)
            __builtin_amdgcn_global_load_lds(
                (const __attribute__((address_space(1))) void*)(Ab + (size_t)(i * 8) * lda + k0),
                (__attribute__((address_space(3))) void*)&As[w * RA + i * 8][0],
                16, 0, 0);
#pragma unroll
        for (int i = 0; i < IB; ++i)
            __builtin_amdgcn_global_load_lds(
                (const __attribute__((address_space(1))) void*)(Bb + (size_t)(i * 8) * ldb + k0),
                (__attribute__((address_space(3))) void*)&Bs[w * RB + i * 8][0],
                16, 0, 0);
        __syncthreads();
#pragma unroll
        for (int kh = 0; kh < 2; ++kh) {
            const int slot = (kh * 4 + (l >> 4)) ^ (l & 7);
            bf16x8 af[FM], bfr[FN];
#pragma unroll
            for (int mt = 0; mt < FM; ++mt)
                af[mt] = As[wm * WM + mt * 16 + (l & 15)][slot];
#pragma unroll
            for (int nt = 0; nt < FN; ++nt)
                bfr[nt] = Bs[wn * WN + nt * 16 + (l & 15)][slot];
#pragma unroll
            for (int mt = 0; mt < FM; ++mt)
#pragma unroll
                for (int nt = 0; nt < FN; ++nt)
                    acc[mt][nt] = __builtin_amdgcn_mfma_f32_16x16x32_bf16(
                        af[mt], bfr[nt], acc[mt][nt], 0, 0, 0);
        }
        __syncthreads();
    }

    const int cr = (l >> 4) * 4, cc = l & 15;
#pragma unroll
    for (int mt = 0; mt < FM; ++mt) {
#pragma unroll
        for (int nt = 0; nt < FN; ++nt) {
            const int gc = bcol + wn * WN + nt * 16 + cc;
            const float bv = bias ? bias[gc] : 0.f;
#pragma unroll
            for (int r = 0; r < 4; ++r) {
                const size_t gr = (size_t)brow + wm * WM + mt * 16 + cr + r;
                float v = acc[mt][nt][r] * scale + bv;
                if (GELU) v = 0.5f * v * (1.f + erff(v * 0.70710678118654752f));
                if (res) v += bf2f(res[gr * ldr + gc]);
                if (OUTBF) ((ushort*)Cp)[gr * ldc + gc] = f2bf(v);
                else       ((float*)Cp)[gr * ldc + gc]  = v;
            }
        }
    }
}

// ---------------------------------------------------------------------------
// 256x256 v-GEMM, barrier-minimal pipeline, plain 2-D grid (r13/r14, proven).
// ---------------------------------------------------------------------------
__global__ __launch_bounds__(512, 2) void gemm_v256_k(
    const ushort* __restrict__ A,        // featb [BTOT][INP]
    const ushort* __restrict__ BT,       // WfvT [ENW][INP]
    const float* __restrict__ bias,      // bfv + ENW
    ushort* __restrict__ C)              // vb [BTOT][ENW]
{
    __shared__ bf16x8 lds[2][2][256][8];   // [dbuf][A/B][row][16B chunk]
    const int tid = threadIdx.x;
    const int l = tid & 63, w = tid >> 6;
    const int wm = w >> 2, wn = w & 3;      // 2 x 4 wave grid
    const int brow = blockIdx.y * 256, bcol = blockIdx.x * 256;
    const int lr = l >> 3, ls = (l & 7) ^ lr;

    const ushort* Ab = A  + (size_t)(brow + w * 8 + lr) * INP + ls * 8;
    const ushort* Bb = BT + (size_t)(bcol + w * 8 + lr) * INP + ls * 8;

#define STAGE_T(d, t) do { const int k0s = (t) * 64;                          \
    _Pragma("unroll")                                                          \
    for (int g = 0; g < 4; ++g)                                                \
        __builtin_amdgcn_global_load_lds(                                      \
            (const __attribute__((address_space(1))) void*)(Ab + (size_t)(g * 64) * INP + k0s), \
            (__attribute__((address_space(3))) void*)&lds[d][0][g * 64 + w * 8][0], 16, 0, 0);  \
    _Pragma("unroll")                                                          \
    for (int g = 0; g < 4; ++g)                                                \
        __builtin_amdgcn_global_load_lds(                                      \
            (const __attribute__((address_space(1))) void*)(Bb + (size_t)(g * 64) * INP + k0s), \
            (__attribute__((address_space(3))) void*)&lds[d][1][g * 64 + w * 8][0], 16, 0, 0);  \
} while (0)

#define RD_A(dst, dd, rh, kh) do {                                             \
    const int slot_ = ((kh) * 4 + (l >> 4)) ^ (l & 7);                         \
    _Pragma("unroll")                                                          \
    for (int mt = 0; mt < 4; ++mt)                                             \
        dst[mt] = lds[dd][0][wm * 128 + (rh) * 64 + mt * 16 + (l & 15)][slot_]; \
} while (0)

#define RD_B(dd, kh) do {                                                      \
    const int slot_ = ((kh) * 4 + (l >> 4)) ^ (l & 7);                         \
    _Pragma("unroll")                                                          \
    for (int nt = 0; nt < 4; ++nt)                                             \
        bfr[nt][kh] = lds[dd][1][wn * 64 + nt * 16 + (l & 15)][slot_];         \
} while (0)

#define MFMA4(base, af, kh) do {                                               \
    __builtin_amdgcn_s_setprio(1);                                             \
    _Pragma("unroll")                                                          \
    for (int mt = 0; mt < 4; ++mt)                                             \
        _Pragma("unroll")                                                      \
        for (int nt = 0; nt < 4; ++nt)                                         \
            acc[(base) + mt][nt] = __builtin_amdgcn_mfma_f32_16x16x32_bf16(    \
                af[mt], bfr[nt][kh], acc[(base) + mt][nt], 0, 0, 0);           \
    __builtin_amdgcn_s_setprio(0);                                             \
} while (0)

    f32x4 acc[8][4];
#pragma unroll
    for (int i = 0; i < 8; ++i)
#pragma unroll
        for (int j = 0; j < 4; ++j) acc[i][j] = (f32x4)0.f;

    // prologue: tiles 0 and 1 in flight; wait tile 0 only.
    STAGE_T(0, 0);
    STAGE_T(1, 1);
    asm volatile("s_waitcnt vmcnt(8)" ::: "memory");
    __builtin_amdgcn_s_barrier();

    bf16x8 aA[4], aB[4], bfr[4][2];
    RD_A(aA, 0, 0, 0);
    RD_B(0, 0);

    const int NT = INP / 64;   // 24
    for (int j = 0; j < NT; ++j) {
        const int d = j & 1;
        if (j > 0 && j + 1 < NT) STAGE_T(d ^ 1, j + 1);
        RD_A(aB, d, 0, 1);          // phase-1 frags
        RD_B(d, 1);
        MFMA4(0, aA, 0);            // phase 0 (rh0,kh0)
        RD_A(aA, d, 1, 0);          // phase-2 frags
        MFMA4(0, aB, 1);            // phase 1 (rh0,kh1)
        RD_A(aB, d, 1, 1);          // phase-3 frags
        MFMA4(4, aA, 0);            // phase 2 (rh1,kh0)
        MFMA4(4, aB, 1);            // phase 3 (rh1,kh1)
        __syncthreads();            // drains vmcnt(0): tile j+1 staged + all
                                    // waves done reading buffer d
        if (j + 1 < NT) {           // pre-issue next tile's phase-0 frags
            RD_A(aA, d ^ 1, 0, 0);
            RD_B(d ^ 1, 0);
        }
    }
#undef STAGE_T
#undef RD_A
#undef RD_B
#undef MFMA4

    const int cr = (l >> 4) * 4, cc = l & 15;
#pragma unroll
    for (int h = 0; h < 2; ++h)
#pragma unroll
        for (int mt = 0; mt < 4; ++mt)
#pragma unroll
            for (int nt = 0; nt < 4; ++nt) {
                const int gc = bcol + wn * 64 + nt * 16 + cc;
                const float bv = bias[gc];
#pragma unroll
                for (int r = 0; r < 4; ++r) {
                    const size_t gr = (size_t)brow + wm * 128 + h * 64 + mt * 16 + cr + r;
                    C[gr * ENW + gc] = f2bf(acc[h * 4 + mt][nt][r] + bv);
                }
            }
}

// ---------------------------------------------------------------------------
// Bucketed dots GEMM + in-epilogue log-softmax (proven).
// ---------------------------------------------------------------------------
__global__ __launch_bounds__(256) void gemm_dots_k(
    const ushort* __restrict__ A,
    const ushort* __restrict__ BT,
    const int* __restrict__ perm, const int* __restrict__ boff,
    const float* __restrict__ C0s, float* __restrict__ Csel)
{
    const int bucket = blockIdx.y;
    const int off = boff[bucket], end = boff[bucket + 1];
    const int tile = blockIdx.x;
    if (tile * 128 >= end - off) return;

    __shared__ bf16x8 As[128][8];
    __shared__ bf16x8 Bs[128][8];
    const int tid = threadIdx.x;
    const int l = tid & 63, w = tid >> 6;
    const int wm = w >> 1, wn = w & 1;
    const int lr = l >> 3;
    const int ls = (l & 7) ^ lr;

    int rowidx[4];
#pragma unroll
    for (int i = 0; i < 4; ++i) {
        int rg = off + tile * 128 + w * 32 + lr + i * 8;
        rowidx[i] = perm[rg < end ? rg : off];
    }
    const ushort* Bb = BT + (size_t)(bucket * 128 + w * 32 + lr) * INP + ls * 8;

    f32x4 acc[4][4];
#pragma unroll
    for (int i = 0; i < 4; ++i)
#pragma unroll
        for (int j = 0; j < 4; ++j) acc[i][j] = (f32x4)0.f;

    for (int k0 = 0; k0 < INP; k0 += 64) {
#pragma unroll
        for (int i = 0; i < 4; ++i)
            __builtin_amdgcn_global_load_lds(
                (const __attribute__((address_space(1))) void*)(
                    A + (size_t)rowidx[i] * INP + ls * 8 + k0),
                (__attribute__((address_space(3))) void*)&As[w * 32 + i * 8][0],
                16, 0, 0);
#pragma unroll
        for (int i = 0; i < 4; ++i)
            __builtin_amdgcn_global_load_lds(
                (const __attribute__((address_space(1))) void*)(
                    Bb + (size_t)(i * 8) * INP + k0),
                (__attribute__((address_space(3))) void*)&Bs[w * 32 + i * 8][0],
                16, 0, 0);
        __syncthreads();
#pragma unroll
        for (int kh = 0; kh < 2; ++kh) {
            const int slot = (kh * 4 + (l >> 4)) ^ (l & 7);
            bf16x8 af[4], bfr[4];
#pragma unroll
            for (int mt = 0; mt < 4; ++mt)
                af[mt] = As[wm * 64 + mt * 16 + (l & 15)][slot];
#pragma unroll
            for (int nt = 0; nt < 4; ++nt)
                bfr[nt] = Bs[wn * 64 + nt * 16 + (l & 15)][slot];
#pragma unroll
            for (int mt = 0; mt < 4; ++mt)
#pragma unroll
                for (int nt = 0; nt < 4; ++nt)
                    acc[mt][nt] = __builtin_amdgcn_mfma_f32_16x16x32_bf16(
                        af[mt], bfr[nt], acc[mt][nt], 0, 0, 0);
        }
        __syncthreads();
    }

    const int cr = (l >> 4) * 4, cc = l & 15;
#pragma unroll
    for (int mt = 0; mt < 4; ++mt) {
#pragma unroll
        for (int nt = 0; nt < 4; ++nt) {
            const int gc = wn * 64 + nt * 16 + cc;
            const float bv = C0s[bucket * 128 + gc];
#pragma unroll
            for (int r = 0; r < 4; ++r) {
                float val = acc[mt][nt][r] * 0.125f + bv;
                float mx = val;
                mx = fmaxf(mx, __shfl_xor(mx, 1, 64));
                mx = fmaxf(mx, __shfl_xor(mx, 2, 64));
                mx = fmaxf(mx, __shfl_xor(mx, 4, 64));
                mx = fmaxf(mx, __shfl_xor(mx, 8, 64));
                float e = expf(val - mx);
                e += __shfl_xor(e, 1, 64);
                e += __shfl_xor(e, 2, 64);
                e += __shfl_xor(e, 4, 64);
                e += __shfl_xor(e, 8, 64);
                const float lse = mx + logf(e);
                int rg = off + tile * 128 + wm * 64 + mt * 16 + cr + r;
                int orow = perm[rg < end ? rg : off];
                Csel[(size_t)orow * 128 + gc] = val - lse;
            }
        }
    }
}

// ---------------------------------------------------------------------------
// Layer-0 attend: weights = dsel log-probs (precomputed), v bf16.
// ---------------------------------------------------------------------------
__global__ __launch_bounds__(512) void attend0_k(
    const float* __restrict__ dsel, const ushort* __restrict__ vb,
    ushort* __restrict__ o)
{
    const int bt = blockIdx.x;
    const int l  = threadIdx.x & 63;
    const int h  = threadIdx.x >> 6;
    const int dg = l & 7, mg = l >> 3;

    const float w0 = dsel[(size_t)bt * 128 + h * 16 + mg];
    const float w1 = dsel[(size_t)bt * 128 + h * 16 + 8 + mg];

    const ushort* base = vb + (size_t)bt * ENW + h * 64 + dg * 8;
    uint4 v0 = *reinterpret_cast<const uint4*>(base + (size_t)mg * EDIM);
    uint4 v1 = *reinterpret_cast<const uint4*>(base + (size_t)(8 + mg) * EDIM);
    const ushort* u0 = reinterpret_cast<const ushort*>(&v0);
    const ushort* u1 = reinterpret_cast<const ushort*>(&v1);
    float acc[8];
#pragma unroll
    for (int j = 0; j < 8; ++j)
        acc[j] = w0 * bf2f(u0[j]) + w1 * bf2f(u1[j]);
#pragma unroll
    for (int off = 8; off < 64; off <<= 1)
#pragma unroll
        for (int j = 0; j < 8; ++j) acc[j] += __shfl_xor(acc[j], off, 64);

    if (mg == 0) {
        uint4 pk;
        pk.x = f2bf(acc[0]) | ((unsigned)f2bf(acc[1]) << 16);
        pk.y = f2bf(acc[2]) | ((unsigned)f2bf(acc[3]) << 16);
        pk.z = f2bf(acc[4]) | ((unsigned)f2bf(acc[5]) << 16);
        pk.w = f2bf(acc[6]) | ((unsigned)f2bf(acc[7]) << 16);
        *reinterpret_cast<uint4*>(o + (size_t)bt * EDIM + h * 64 + dg * 8) = pk;
    }
}

// ---------------------------------------------------------------------------
// Row LayerNorm over E=512: one wave per row; emits bf16 ONLY (r14).
// ---------------------------------------------------------------------------
__global__ __launch_bounds__(256) void ln_k(
    const float* __restrict__ x, const float* __restrict__ g,
    const float* __restrict__ b, ushort* __restrict__ yb)
{
    const int row = blockIdx.x * 4 + (threadIdx.x >> 6);
    const int lane = threadIdx.x & 63;
    const float* xr = x + (size_t)row * EDIM + lane * 8;
    float4 a0 = *reinterpret_cast<const float4*>(xr);
    float4 a1 = *reinterpret_cast<const float4*>(xr + 4);
    float v[8] = {a0.x, a0.y, a0.z, a0.w, a1.x, a1.y, a1.z, a1.w};

    float s = 0.f;
#pragma unroll
    for (int j = 0; j < 8; ++j) s += v[j];
#pragma unroll
    for (int off = 32; off; off >>= 1) s += __shfl_xor(s, off, 64);
    const float m = s * (1.f / 512.f);

    float q = 0.f;
#pragma unroll
    for (int j = 0; j < 8; ++j) { float d = v[j] - m; q = fmaf(d, d, q); }
#pragma unroll
    for (int off = 32; off; off >>= 1) q += __shfl_xor(q, off, 64);
    const float inv = rsqrtf(q * (1.f / 512.f) + 1e-5f);

    const int c = lane * 8;
    float4 g0 = *reinterpret_cast<const float4*>(g + c);
    float4 g1 = *reinterpret_cast<const float4*>(g + c + 4);
    float4 b0 = *reinterpret_cast<const float4*>(b + c);
    float4 b1 = *reinterpret_cast<const float4*>(b + c + 4);
    float gg[8] = {g0.x, g0.y, g0.z, g0.w, g1.x, g1.y, g1.z, g1.w};
    float bb[8] = {b0.x, b0.y, b0.z, b0.w, b1.x, b1.y, b1.z, b1.w};
    float out[8];
#pragma unroll
    for (int j = 0; j < 8; ++j) out[j] = (v[j] - m) * inv * gg[j] + bb[j];
    uint4 p;
    p.x = f2bf(out[0]) | ((unsigned)f2bf(out[1]) << 16);
    p.y = f2bf(out[2]) | ((unsigned)f2bf(out[3]) << 16);
    p.z = f2bf(out[4]) | ((unsigned)f2bf(out[5]) << 16);
    p.w = f2bf(out[6]) | ((unsigned)f2bf(out[7]) << 16);
    *reinterpret_cast<uint4*>(yb + (size_t)row * EDIM + c) = p;
}

// out[row] = x[row,:] . Wm + bm
__global__ __launch_bounds__(256) void final_k(
    const float* __restrict__ x, const float* __restrict__ Wm,
    const float* __restrict__ bm, float* __restrict__ out)
{
    const int row = blockIdx.x * 4 + (threadIdx.x >> 6);
    const int lane = threadIdx.x & 63;
    const float* xr = x + (size_t)row * EDIM + lane * 8;
    const float* wr = Wm + lane * 8;
    float s = 0.f;
#pragma unroll
    for (int j = 0; j < 8; ++j) s = fmaf(xr[j], wr[j], s);
#pragma unroll
    for (int off = 32; off; off >>= 1) s += __shfl_xor(s, off, 64);
    if (lane == 0) out[row] = s + bm[0];
}

// ---------------------------------------------------------------------------
extern "C" void kernel_launch(void* const* d_in, const int* in_sizes, int n_in,
                              void* d_out, int out_size, void* d_ws, size_t ws_size,
                              hipStream_t stream)
{
    (void)in_sizes; (void)n_in; (void)out_size; (void)ws_size;
    const float* features = (const float*)d_in[0];
    const int*   targets  = (const int*)d_in[1];
    const float* emb      = (const float*)d_in[2];
    const float* Wf       = (const float*)d_in[3];
    const float* bfv      = (const float*)d_in[4];
    const float* a0Wo     = (const float*)d_in[5];
    const float* a0bo     = (const float*)d_in[6];
    const float* Wm       = (const float*)d_in[7];
    const float* bm       = (const float*)d_in[8];
    const float *ffg[3], *ffb[3], *W1[3], *b1[3], *W2[3], *b2[3];
    for (int i = 0; i < 3; ++i) {
        ffg[i] = (const float*)d_in[9 + 6 * i];
        ffb[i] = (const float*)d_in[10 + 6 * i];
        W1[i]  = (const float*)d_in[11 + 6 * i];
        b1[i]  = (const float*)d_in[12 + 6 * i];
        W2[i]  = (const float*)d_in[13 + 6 * i];
        b2[i]  = (const float*)d_in[14 + 6 * i];
    }
    const float *ag[2], *abp[2], *aWqkv[2], *aWo[2], *abo[2];
    for (int i = 0; i < 2; ++i) {
        ag[i]    = (const float*)d_in[27 + 5 * i];
        abp[i]   = (const float*)d_in[28 + 5 * i];
        aWqkv[i] = (const float*)d_in[29 + 5 * i];
        aWo[i]   = (const float*)d_in[30 + 5 * i];
        abo[i]   = (const float*)d_in[31 + 5 * i];
    }

    // ---- workspace carve-up ----
    char* wsc = (char*)d_ws;
    auto alloc = [&](size_t bytes) { char* p = wsc; wsc += bytes; return p; };
    ushort* WfvT  = (ushort*)alloc((size_t)ENW * INP * 2);       // 25.2 MB
    ushort* BTg   = (ushort*)alloc((size_t)NDOT * INP * 2);      // 6.3 MB
    float*  C0s   = (float*) alloc((size_t)NDOT * 4);
    float*  dsel  = (float*) alloc((size_t)BTOT * 128 * 4);      // 2.1 MB
    int*    perm  = (int*)   alloc((size_t)BTOT * 4);
    int*    boff  = (int*)   alloc(32 * 4);
    ushort* a0WoT = (ushort*)alloc((size_t)EDIM * EDIM * 2);
    ushort *W1T[3], *W2T[3], *WoT[2], *Wv_bf[2], *WcombT[2];
    for (int i = 0; i < 3; ++i) {
        W1T[i] = (ushort*)alloc((size_t)FFH * EDIM * 2);
        W2T[i] = (ushort*)alloc((size_t)EDIM * FFH * 2);
    }
    for (int i = 0; i < 2; ++i) {
        WoT[i]    = (ushort*)alloc((size_t)EDIM * EDIM * 2);
        Wv_bf[i]  = (ushort*)alloc((size_t)EDIM * EDIM * 2);
        WcombT[i] = (ushort*)alloc((size_t)EDIM * EDIM * 2);
    }
    ushort* featb = (ushort*)alloc((size_t)BTOT * INP * 2);      // 12.6 MB
    ushort* o_b   = (ushort*)alloc((size_t)BTOT * EDIM * 2);     // 4.2 MB
    float*  x     = (float*) alloc((size_t)BTOT * EDIM * 4);     // 8.4 MB
    ushort* xlnb  = (ushort*)alloc((size_t)BTOT * EDIM * 2);
    ushort* hb    = (ushort*)alloc((size_t)BTOT * FFH * 2);      // 8.4 MB
    ushort* vb    = (ushort*)alloc((size_t)BTOT * ENW * 2);      // 67 MB

    const dim3 blk(256, 1, 1);

    // ---- prep: 3 separate dispatches (r8 structure — measured faster) ----
    conv_all_k<<<3328, blk, 0, stream>>>(features, featb,
                                         aWqkv[0], aWqkv[1], Wv_bf[0], Wv_bf[1]);
    gproj_k<<<dim3(128, 9), blk, 0, stream>>>(Wf, bfv, emb, BTg, C0s,
                                              targets, perm, boff);

    TJobs tj;
    int ob = 0, ji = 0;
    auto addj = [&](const float* in, ushort* out, int ld, int c0, int R,
                    int gbx, int gby) {
        tj.j[ji++] = {in, out, ld, c0, R, gbx, ob};
        ob += gbx * gby;
    };
    addj(Wf, WfvT, KVW, ENW, INP, 128, 24);       // v-half of Wf (3072 blocks)
    addj(a0Wo, a0WoT, EDIM, 0, EDIM, 8, 8);
    for (int i = 0; i < 3; ++i) {
        addj(W1[i], W1T[i], FFH, 0, EDIM, 16, 8);
        addj(W2[i], W2T[i], EDIM, 0, FFH, 8, 16);
    }
    addj(aWo[0], WoT[0], EDIM, 0, EDIM, 8, 8);
    addj(aWo[1], WoT[1], EDIM, 0, EDIM, 8, 8);
    transpose_all_k<<<ob, blk, 0, stream>>>(tj);

    // ---- layer 0 ----
    const float CATT = -44.36141955583650f;   // -16*ln(16)
    gemm_dots_k<<<dim3(32, 16), blk, 0, stream>>>(featb, BTg, perm, boff,
                                                  C0s, dsel);
    for (int i = 0; i < 2; ++i)
        gemm_mfma_k<64, 128, 32, 64, 4, false, true>
            <<<dim3(EDIM / 128, EDIM / 64), blk, 0, stream>>>(
            WoT[i], EDIM, Wv_bf[i], EDIM, WcombT[i], EDIM, EDIM,
            nullptr, nullptr, 0, CATT);
    gemm_v256_k<<<dim3(ENW / 256, BTOT / 256), dim3(512, 1, 1), 0, stream>>>(
        featb, WfvT, bfv + ENW, vb);
    attend0_k<<<BTOT, 512, 0, stream>>>(dsel, vb, o_b);
    gemm_mfma_k<64, 128, 32, 64, 4, false, false>
        <<<dim3(EDIM / 128, BTOT / 64), blk, 0, stream>>>(
        o_b, EDIM, a0WoT, EDIM, x, EDIM, EDIM, a0bo, nullptr, 0, 1.f);

    auto ln = [&](const float* g, const float* b) {
        ln_k<<<BTOT / 4, blk, 0, stream>>>(x, g, b, xlnb);
    };
    auto ff = [&](int i) {
        ln(ffg[i], ffb[i]);
        gemm_mfma_k<64, 128, 32, 64, 4, true, true>
            <<<dim3(FFH / 128, BTOT / 64), blk, 0, stream>>>(
            xlnb, EDIM, W1T[i], EDIM, hb, FFH, EDIM, b1[i], nullptr, 0, 1.f);
        gemm_mfma_k<64, 128, 32, 64, 4, false, false>
            <<<dim3(EDIM / 128, BTOT / 64), blk, 0, stream>>>(
            hb, FFH, W2T[i], FFH, x, EDIM, FFH, b2[i], xlnb, EDIM, 1.f);
    };
    auto attn = [&](int i) {
        ln(ag[i], abp[i]);
        gemm_mfma_k<64, 128, 32, 64, 4, false, false>
            <<<dim3(EDIM / 128, BTOT / 64), blk, 0, stream>>>(
            xlnb, EDIM, WcombT[i], EDIM, x, EDIM, EDIM, abo[i], xlnb, EDIM, 1.f);
    };

    ff(0);
    attn(0);
    ff(1);
    attn(1);
    ff(2);

    final_k<<<BTOT / 4, blk, 0, stream>>>(x, Wm, bm, (float*)d_out);
}

// Round 17
// 413.416 us; speedup vs baseline: 1.2153x; 1.0515x over previous
//
#include <hip/hip_runtime.h>
#include <math.h>

// MixedHead: B=16,T=256 -> BT=4096; INP=1536; E=512; H=8; N=16; D=64.
#define BTOT 4096
#define INP  1536
#define EDIM 512
#define NTOK 16
#define KVW  16384   // 2*E*N
#define ENW  8192    // E*N
#define FFH  1024    // 2*E
#define NDOT 2048    // 16 targets x 128 (h,m)

typedef __attribute__((ext_vector_type(8))) __bf16 bf16x8;
typedef __attribute__((ext_vector_type(4))) float f32x4;

__device__ __forceinline__ ushort f2bf(float f) {
    union { float f; unsigned u; } v; v.f = f;
    unsigned r = v.u + 0x7fffu + ((v.u >> 16) & 1u);
    return (ushort)(r >> 16);
}
__device__ __forceinline__ float bf2f(ushort h) {
    union { unsigned u; float f; } v; v.u = ((unsigned)h) << 16;
    return v.f;
}

// ---------------------------------------------------------------------------
// Transpose f32 [R][ld] (cols c0..) -> bf16 [C][R]. 10 jobs, one launch (r8).
// ---------------------------------------------------------------------------
__device__ __forceinline__ void transpose_body(
    const float* in, int ld, int c0, int R, ushort* out,
    int bx, int by, int tid)
{
    __shared__ float t[64][65];
    const int bc = bx * 64 + c0;
    const int br = by * 64;
#pragma unroll
    for (int it = 0; it < 16; ++it) {
        int idx = tid + it * 256;
        int r = idx >> 6, c = idx & 63;
        t[r][c] = in[(size_t)(br + r) * ld + bc + c];
    }
    __syncthreads();
    const int C0 = bx * 64;
#pragma unroll
    for (int it = 0; it < 4; ++it) {
        int idx = tid + it * 256;          // 1024 = 64 cols x 16 row-quads
        int cc = idx >> 4, rp = idx & 15;
        uint2 w2;
        w2.x = f2bf(t[4 * rp + 0][cc]) | ((unsigned)f2bf(t[4 * rp + 1][cc]) << 16);
        w2.y = f2bf(t[4 * rp + 2][cc]) | ((unsigned)f2bf(t[4 * rp + 3][cc]) << 16);
        *reinterpret_cast<uint2*>(out + (size_t)(C0 + cc) * R + br + 4 * rp) = w2;
    }
}

struct TJob { const float* in; ushort* out; int ld, c0, R, gbx, boffs; };
struct TJobs { TJob j[10]; };

__global__ __launch_bounds__(256) void transpose_all_k(TJobs jobs)
{
    const int b = blockIdx.x;
    int ji = 0;
    while (ji < 9 && b >= jobs.j[ji + 1].boffs) ++ji;
    TJob jb = jobs.j[ji];
    const int rel = b - jb.boffs;
    transpose_body(jb.in, jb.ld, jb.c0, jb.R, jb.out,
                   rel % jb.gbx, rel / jb.gbx, threadIdx.x);
}

// ---------------------------------------------------------------------------
// Merged converts (r8): [0,3072) features->bf16; [3072,3328) Wqkv v-slices.
// ---------------------------------------------------------------------------
__global__ __launch_bounds__(256) void conv_all_k(
    const float* __restrict__ features, ushort* __restrict__ featb,
    const float* __restrict__ wq0, const float* __restrict__ wq1,
    ushort* __restrict__ wv0, ushort* __restrict__ wv1)
{
    const int b = blockIdx.x;
    if (b < 3072) {
        const int i = b * 256 + threadIdx.x;          // < 786432
        const float4* p = reinterpret_cast<const float4*>(features) + 2 * (size_t)i;
        float4 a = p[0], c = p[1];
        uint4 o;
        o.x = f2bf(a.x) | ((unsigned)f2bf(a.y) << 16);
        o.y = f2bf(a.z) | ((unsigned)f2bf(a.w) << 16);
        o.z = f2bf(c.x) | ((unsigned)f2bf(c.y) << 16);
        o.w = f2bf(c.z) | ((unsigned)f2bf(c.w) << 16);
        reinterpret_cast<uint4*>(featb)[i] = o;
    } else {
        const int bb = b - 3072;
        const float* src = (bb >= 128) ? wq1 : wq0;
        ushort* dst = (bb >= 128) ? wv1 : wv0;
        const int idx = (bb & 127) * 256 + threadIdx.x;   // < 32768
        const int row = idx >> 6, c8 = (idx & 63) * 8;
        const float4* p = reinterpret_cast<const float4*>(
            src + (size_t)row * (3 * EDIM) + 2 * EDIM + c8);
        float4 a = p[0], c = p[1];
        uint4 o;
        o.x = f2bf(a.x) | ((unsigned)f2bf(a.y) << 16);
        o.y = f2bf(a.z) | ((unsigned)f2bf(a.w) << 16);
        o.z = f2bf(c.x) | ((unsigned)f2bf(c.y) << 16);
        o.w = f2bf(c.z) | ((unsigned)f2bf(c.w) << 16);
        *reinterpret_cast<uint4*>(dst + (size_t)row * EDIM + c8) = o;
    }
}

// ---------------------------------------------------------------------------
// G projection + embedded targets counting sort (r8, grid (128,9)).
// ---------------------------------------------------------------------------
__global__ __launch_bounds__(256) void gproj_k(
    const float* __restrict__ Wf, const float* __restrict__ bfv,
    const float* __restrict__ emb, ushort* __restrict__ BTg,
    float* __restrict__ C0s, const int* __restrict__ targets,
    int* __restrict__ perm, int* __restrict__ boff)
{
    if (blockIdx.y == 8) {
        if (blockIdx.x != 0) return;
        __shared__ int cnt[NTOK], off_s[NTOK], cur[NTOK];
        const int tid = threadIdx.x;
        if (tid < NTOK) cnt[tid] = 0;
        __syncthreads();
        for (int i = tid; i < BTOT; i += 256) atomicAdd(&cnt[targets[i]], 1);
        __syncthreads();
        if (tid == 0) {
            int s = 0;
            for (int b = 0; b < NTOK; ++b) { off_s[b] = s; cur[b] = s; s += cnt[b]; }
            for (int b = 0; b < NTOK; ++b) boff[b] = off_s[b];
            boff[NTOK] = s;
        }
        __syncthreads();
        for (int i = tid; i < BTOT; i += 256) {
            int t = targets[i];
            int p = atomicAdd(&cur[t], 1);
            perm[p] = i;
        }
        return;
    }

    const int hm = blockIdx.x;           // h*16 + m
    const int h = hm >> 4, m = hm & 15;
    const int l = threadIdx.x & 63, w = threadIdx.x >> 6;
    const int t = l & 15, isub = l >> 4;
    const int colb = m * 512 + h * 64;
    const int ibase = blockIdx.y * (INP / 8);

    float4 e[16];
#pragma unroll
    for (int q = 0; q < 16; ++q)
        e[q] = *reinterpret_cast<const float4*>(emb + t * EDIM + h * 64 + q * 4);

    const int n = t * 128 + hm;
    for (int i0 = ibase; i0 < ibase + INP / 8; i0 += 16) {
        const int i = i0 + w * 4 + isub;
        const float* wr = Wf + (size_t)i * KVW + colb;
        float acc = 0.f;
#pragma unroll
        for (int q = 0; q < 16; ++q) {
            float4 v4 = *reinterpret_cast<const float4*>(wr + q * 4);
            acc = fmaf(v4.x, e[q].x, fmaf(v4.y, e[q].y,
                  fmaf(v4.z, e[q].z, fmaf(v4.w, e[q].w, acc))));
        }
        BTg[(size_t)n * INP + i] = f2bf(acc);
    }
    if (blockIdx.y == 0 && w == 0 && isub == 0) {
        const float* br = bfv + colb;
        float acc = 0.f;
#pragma unroll
        for (int q = 0; q < 16; ++q) {
            float4 v4 = *reinterpret_cast<const float4*>(br + q * 4);
            acc = fmaf(v4.x, e[q].x, fmaf(v4.y, e[q].y,
                  fmaf(v4.z, e[q].z, fmaf(v4.w, e[q].w, acc))));
        }
        C0s[n] = 0.125f * acc;
    }
}

// ---------------------------------------------------------------------------
// 2-barrier MFMA GEMM (m97 structure) — kept for Wcomb (tiny grids).
// ---------------------------------------------------------------------------
template <int BM, int BN, int WM, int WN, int NW, bool GELU, bool OUTBF>
__global__ __launch_bounds__(NW * 64) void gemm_mfma_k(
    const ushort* __restrict__ A, int lda,
    const ushort* __restrict__ BT, int ldb,
    void* __restrict__ Cp, int ldc, int K,
    const float* __restrict__ bias,
    const ushort* __restrict__ res, int ldr,
    float scale)
{
    static_assert((BM / WM) * (BN / WN) == NW, "wave grid");
    static_assert(BM % (NW * 8) == 0 && BN % (NW * 8) == 0, "staging");
    constexpr int FM = WM / 16, FN = WN / 16;
    constexpr int IA = BM * 8 / (NW * 64), IB = BN * 8 / (NW * 64);
    constexpr int RA = BM / NW, RB = BN / NW;

    __shared__ bf16x8 As[BM][8];
    __shared__ bf16x8 Bs[BN][8];
    const int tid = threadIdx.x;
    const int l   = tid & 63;
    const int w   = tid >> 6;
    const int wm  = w / (BN / WN), wn = w % (BN / WN);
    const int brow = blockIdx.y * BM, bcol = blockIdx.x * BN;

    const int lr = l >> 3;
    const int ls = (l & 7) ^ lr;
    const ushort* Ab = A  + (size_t)(brow + w * RA + lr) * lda + ls * 8;
    const ushort* Bb = BT + (size_t)(bcol + w * RB + lr) * ldb + ls * 8;

    f32x4 acc[FM][FN];
#pragma unroll
    for (int i = 0; i < FM; ++i)
#pragma unroll
        for (int j = 0; j < FN; ++j) acc[i][j] = (f32x4)0.f;

    for (int k0 = 0; k0 < K; k0 += 64) {
#pragma unroll
        for (int i = 0; i < IA; ++i)
            __builtin_amdgcn_global_load_lds(
                (const __attribute__((address_space(1))) void*)(Ab + (size_t)(i * 8) * lda + k0),
                (__attribute__((address_space(3))) void*)&As[w * RA + i * 8][0],
                16, 0, 0);
#pragma unroll
        for (int i = 0; i < IB; ++i)
            __builtin_amdgcn_global_load_lds(
                (const __attribute__((address_space(1))) void*)(Bb + (size_t)(i * 8) * ldb + k0),
                (__attribute__((address_space(3))) void*)&Bs[w * RB + i * 8][0],
                16, 0, 0);
        __syncthreads();
#pragma unroll
        for (int kh = 0; kh < 2; ++kh) {
            const int slot = (kh * 4 + (l >> 4)) ^ (l & 7);
            bf16x8 af[FM], bfr[FN];
#pragma unroll
            for (int mt = 0; mt < FM; ++mt)
                af[mt] = As[wm * WM + mt * 16 + (l & 15)][slot];
#pragma unroll
            for (int nt = 0; nt < FN; ++nt)
                bfr[nt] = Bs[wn * WN + nt * 16 + (l & 15)][slot];
#pragma unroll
            for (int mt = 0; mt < FM; ++mt)
#pragma unroll
                for (int nt = 0; nt < FN; ++nt)
                    acc[mt][nt] = __builtin_amdgcn_mfma_f32_16x16x32_bf16(
                        af[mt], bfr[nt], acc[mt][nt], 0, 0, 0);
        }
        __syncthreads();
    }

    const int cr = (l >> 4) * 4, cc = l & 15;
#pragma unroll
    for (int mt = 0; mt < FM; ++mt) {
#pragma unroll
        for (int nt = 0; nt < FN; ++nt) {
            const int gc = bcol + wn * WN + nt * 16 + cc;
            const float bv = bias ? bias[gc] : 0.f;
#pragma unroll
            for (int r = 0; r < 4; ++r) {
                const size_t gr = (size_t)brow + wm * WM + mt * 16 + cr + r;
                float v = acc[mt][nt][r] * scale + bv;
                if (GELU) v = 0.5f * v * (1.f + erff(v * 0.70710678118654752f));
                if (res) v += bf2f(res[gr * ldr + gc]);
                if (OUTBF) ((ushort*)Cp)[gr * ldc + gc] = f2bf(v);
                else       ((float*)Cp)[gr * ldc + gc]  = v;
            }
        }
    }
}

// ---------------------------------------------------------------------------
// NEW: 64x128 barrier-minimal pipelined layer GEMM — r15's proven-correct
// schedule at the PROVEN grid (4x64 = 256 blocks; r15's regression was the
// halved grid, not the schedule). 4 waves (2x2 of 32x64), LDS 48 KB -> 3
// blocks/CU. Wave grid / K-order / epilogue identical to
// gemm_mfma_k<64,128,32,64,4> -> bit-identical output.
// ---------------------------------------------------------------------------
template <bool GELU, bool OUTBF>
__global__ __launch_bounds__(256, 3) void gemm_pipe64_k(
    const ushort* __restrict__ A, int lda,
    const ushort* __restrict__ BT, int ldb,
    void* __restrict__ Cp, int ldc, int K,
    const float* __restrict__ bias,
    const ushort* __restrict__ res, int ldr,
    float scale)
{
    __shared__ bf16x8 Asl[2][64][8];
    __shared__ bf16x8 Bsl[2][128][8];
    const int tid = threadIdx.x;
    const int l = tid & 63, w = tid >> 6;
    const int wm = w >> 1, wn = w & 1;      // 2 x 2 waves of 32x64
    const int brow = blockIdx.y * 64, bcol = blockIdx.x * 128;
    const int lr = l >> 3, ls = (l & 7) ^ lr;

    const ushort* Ab = A  + (size_t)(brow + w * 16 + lr) * lda + ls * 8;
    const ushort* Bb = BT + (size_t)(bcol + w * 32 + lr) * ldb + ls * 8;

#define STAGE_P(d, t) do { const int k0s = (t) * 64;                          \
    _Pragma("unroll")                                                          \
    for (int g = 0; g < 2; ++g)                                                \
        __builtin_amdgcn_global_load_lds(                                      \
            (const __attribute__((address_space(1))) void*)(Ab + (size_t)(g * 8) * lda + k0s), \
            (__attribute__((address_space(3))) void*)&Asl[d][w * 16 + g * 8][0], 16, 0, 0);    \
    _Pragma("unroll")                                                          \
    for (int g = 0; g < 4; ++g)                                                \
        __builtin_amdgcn_global_load_lds(                                      \
            (const __attribute__((address_space(1))) void*)(Bb + (size_t)(g * 8) * ldb + k0s), \
            (__attribute__((address_space(3))) void*)&Bsl[d][w * 32 + g * 8][0], 16, 0, 0);    \
} while (0)

#define RD_AP(dst, dd, kh) do {                                                \
    const int slot_ = ((kh) * 4 + (l >> 4)) ^ (l & 7);                         \
    _Pragma("unroll")                                                          \
    for (int mt = 0; mt < 2; ++mt)                                             \
        dst[mt] = Asl[dd][wm * 32 + mt * 16 + (l & 15)][slot_];                \
} while (0)

#define RD_BP(dd, kh) do {                                                     \
    const int slot_ = ((kh) * 4 + (l >> 4)) ^ (l & 7);                         \
    _Pragma("unroll")                                                          \
    for (int nt = 0; nt < 4; ++nt)                                             \
        bfr[nt][kh] = Bsl[dd][wn * 64 + nt * 16 + (l & 15)][slot_];            \
} while (0)

#define MFMA_P(af, kh) do {                                                    \
    __builtin_amdgcn_s_setprio(1);                                             \
    _Pragma("unroll")                                                          \
    for (int mt = 0; mt < 2; ++mt)                                             \
        _Pragma("unroll")                                                      \
        for (int nt = 0; nt < 4; ++nt)                                         \
            acc[mt][nt] = __builtin_amdgcn_mfma_f32_16x16x32_bf16(             \
                af[mt], bfr[nt][kh], acc[mt][nt], 0, 0, 0);                    \
    __builtin_amdgcn_s_setprio(0);                                             \
} while (0)

    f32x4 acc[2][4];
#pragma unroll
    for (int i = 0; i < 2; ++i)
#pragma unroll
        for (int j = 0; j < 4; ++j) acc[i][j] = (f32x4)0.f;

    // prologue: tiles 0 and 1 in flight (6 loads each); wait tile 0 only.
    STAGE_P(0, 0);
    STAGE_P(1, 1);
    asm volatile("s_waitcnt vmcnt(6)" ::: "memory");
    __builtin_amdgcn_s_barrier();

    bf16x8 aA[2], aB[2], bfr[4][2];
    RD_AP(aA, 0, 0);
    RD_BP(0, 0);

    const int NT = K / 64;
    for (int j = 0; j < NT; ++j) {
        const int d = j & 1;
        if (j > 0 && j + 1 < NT) STAGE_P(d ^ 1, j + 1);
        RD_AP(aB, d, 1);
        RD_BP(d, 1);
        MFMA_P(aA, 0);
        MFMA_P(aB, 1);
        __syncthreads();            // vmcnt(0)+lgkmcnt(0) drain: tile j+1
                                    // staged, all waves done with buffer d
        if (j + 1 < NT) {
            RD_AP(aA, d ^ 1, 0);
            RD_BP(d ^ 1, 0);
        }
    }
#undef STAGE_P
#undef RD_AP
#undef RD_BP
#undef MFMA_P

    const int cr = (l >> 4) * 4, cc = l & 15;
#pragma unroll
    for (int mt = 0; mt < 2; ++mt) {
#pragma unroll
        for (int nt = 0; nt < 4; ++nt) {
            const int gc = bcol + wn * 64 + nt * 16 + cc;
            const float bv = bias ? bias[gc] : 0.f;
#pragma unroll
            for (int r = 0; r < 4; ++r) {
                const size_t gr = (size_t)brow + wm * 32 + mt * 16 + cr + r;
                float v = acc[mt][nt][r] * scale + bv;
                if (GELU) v = 0.5f * v * (1.f + erff(v * 0.70710678118654752f));
                if (res) v += bf2f(res[gr * ldr + gc]);
                if (OUTBF) ((ushort*)Cp)[gr * ldc + gc] = f2bf(v);
                else       ((float*)Cp)[gr * ldc + gc]  = v;
            }
        }
    }
}

// ---------------------------------------------------------------------------
// 256x256 v-GEMM, barrier-minimal pipeline, plain 2-D grid (r13/r14, proven).
// ---------------------------------------------------------------------------
__global__ __launch_bounds__(512, 2) void gemm_v256_k(
    const ushort* __restrict__ A,        // featb [BTOT][INP]
    const ushort* __restrict__ BT,       // WfvT [ENW][INP]
    const float* __restrict__ bias,      // bfv + ENW
    ushort* __restrict__ C)              // vb [BTOT][ENW]
{
    __shared__ bf16x8 lds[2][2][256][8];   // [dbuf][A/B][row][16B chunk]
    const int tid = threadIdx.x;
    const int l = tid & 63, w = tid >> 6;
    const int wm = w >> 2, wn = w & 3;      // 2 x 4 wave grid
    const int brow = blockIdx.y * 256, bcol = blockIdx.x * 256;
    const int lr = l >> 3, ls = (l & 7) ^ lr;

    const ushort* Ab = A  + (size_t)(brow + w * 8 + lr) * INP + ls * 8;
    const ushort* Bb = BT + (size_t)(bcol + w * 8 + lr) * INP + ls * 8;

#define STAGE_T(d, t) do { const int k0s = (t) * 64;                          \
    _Pragma("unroll")                                                          \
    for (int g = 0; g < 4; ++g)                                                \
        __builtin_amdgcn_global_load_lds(                                      \
            (const __attribute__((address_space(1))) void*)(Ab + (size_t)(g * 64) * INP + k0s), \
            (__attribute__((address_space(3))) void*)&lds[d][0][g * 64 + w * 8][0], 16, 0, 0);  \
    _Pragma("unroll")                                                          \
    for (int g = 0; g < 4; ++g)                                                \
        __builtin_amdgcn_global_load_lds(                                      \
            (const __attribute__((address_space(1))) void*)(Bb + (size_t)(g * 64) * INP + k0s), \
            (__attribute__((address_space(3))) void*)&lds[d][1][g * 64 + w * 8][0], 16, 0, 0);  \
} while (0)

#define RD_A(dst, dd, rh, kh) do {                                             \
    const int slot_ = ((kh) * 4 + (l >> 4)) ^ (l & 7);                         \
    _Pragma("unroll")                                                          \
    for (int mt = 0; mt < 4; ++mt)                                             \
        dst[mt] = lds[dd][0][wm * 128 + (rh) * 64 + mt * 16 + (l & 15)][slot_]; \
} while (0)

#define RD_B(dd, kh) do {                                                      \
    const int slot_ = ((kh) * 4 + (l >> 4)) ^ (l & 7);                         \
    _Pragma("unroll")                                                          \
    for (int nt = 0; nt < 4; ++nt)                                             \
        bfr[nt][kh] = lds[dd][1][wn * 64 + nt * 16 + (l & 15)][slot_];         \
} while (0)

#define MFMA4(base, af, kh) do {                                               \
    __builtin_amdgcn_s_setprio(1);                                             \
    _Pragma("unroll")                                                          \
    for (int mt = 0; mt < 4; ++mt)                                             \
        _Pragma("unroll")                                                      \
        for (int nt = 0; nt < 4; ++nt)                                         \
            acc[(base) + mt][nt] = __builtin_amdgcn_mfma_f32_16x16x32_bf16(    \
                af[mt], bfr[nt][kh], acc[(base) + mt][nt], 0, 0, 0);           \
    __builtin_amdgcn_s_setprio(0);                                             \
} while (0)

    f32x4 acc[8][4];
#pragma unroll
    for (int i = 0; i < 8; ++i)
#pragma unroll
        for (int j = 0; j < 4; ++j) acc[i][j] = (f32x4)0.f;

    // prologue: tiles 0 and 1 in flight; wait tile 0 only.
    STAGE_T(0, 0);
    STAGE_T(1, 1);
    asm volatile("s_waitcnt vmcnt(8)" ::: "memory");
    __builtin_amdgcn_s_barrier();

    bf16x8 aA[4], aB[4], bfr[4][2];
    RD_A(aA, 0, 0, 0);
    RD_B(0, 0);

    const int NT = INP / 64;   // 24
    for (int j = 0; j < NT; ++j) {
        const int d = j & 1;
        if (j > 0 && j + 1 < NT) STAGE_T(d ^ 1, j + 1);
        RD_A(aB, d, 0, 1);          // phase-1 frags
        RD_B(d, 1);
        MFMA4(0, aA, 0);            // phase 0 (rh0,kh0)
        RD_A(aA, d, 1, 0);          // phase-2 frags
        MFMA4(0, aB, 1);            // phase 1 (rh0,kh1)
        RD_A(aB, d, 1, 1);          // phase-3 frags
        MFMA4(4, aA, 0);            // phase 2 (rh1,kh0)
        MFMA4(4, aB, 1);            // phase 3 (rh1,kh1)
        __syncthreads();            // drains vmcnt(0): tile j+1 staged + all
                                    // waves done reading buffer d
        if (j + 1 < NT) {           // pre-issue next tile's phase-0 frags
            RD_A(aA, d ^ 1, 0, 0);
            RD_B(d ^ 1, 0);
        }
    }
#undef STAGE_T
#undef RD_A
#undef RD_B
#undef MFMA4

    const int cr = (l >> 4) * 4, cc = l & 15;
#pragma unroll
    for (int h = 0; h < 2; ++h)
#pragma unroll
        for (int mt = 0; mt < 4; ++mt)
#pragma unroll
            for (int nt = 0; nt < 4; ++nt) {
                const int gc = bcol + wn * 64 + nt * 16 + cc;
                const float bv = bias[gc];
#pragma unroll
                for (int r = 0; r < 4; ++r) {
                    const size_t gr = (size_t)brow + wm * 128 + h * 64 + mt * 16 + cr + r;
                    C[gr * ENW + gc] = f2bf(acc[h * 4 + mt][nt][r] + bv);
                }
            }
}

// ---------------------------------------------------------------------------
// Bucketed dots GEMM + in-epilogue log-softmax (proven).
// ---------------------------------------------------------------------------
__global__ __launch_bounds__(256) void gemm_dots_k(
    const ushort* __restrict__ A,
    const ushort* __restrict__ BT,
    const int* __restrict__ perm, const int* __restrict__ boff,
    const float* __restrict__ C0s, float* __restrict__ Csel)
{
    const int bucket = blockIdx.y;
    const int off = boff[bucket], end = boff[bucket + 1];
    const int tile = blockIdx.x;
    if (tile * 128 >= end - off) return;

    __shared__ bf16x8 As[128][8];
    __shared__ bf16x8 Bs[128][8];
    const int tid = threadIdx.x;
    const int l = tid & 63, w = tid >> 6;
    const int wm = w >> 1, wn = w & 1;
    const int lr = l >> 3;
    const int ls = (l & 7) ^ lr;

    int rowidx[4];
#pragma unroll
    for (int i = 0; i < 4; ++i) {
        int rg = off + tile * 128 + w * 32 + lr + i * 8;
        rowidx[i] = perm[rg < end ? rg : off];
    }
    const ushort* Bb = BT + (size_t)(bucket * 128 + w * 32 + lr) * INP + ls * 8;

    f32x4 acc[4][4];
#pragma unroll
    for (int i = 0; i < 4; ++i)
#pragma unroll
        for (int j = 0; j < 4; ++j) acc[i][j] = (f32x4)0.f;

    for (int k0 = 0; k0 < INP; k0 += 64) {
#pragma unroll
        for (int i = 0; i < 4; ++i)
            __builtin_amdgcn_global_load_lds(
                (const __attribute__((address_space(1))) void*)(
                    A + (size_t)rowidx[i] * INP + ls * 8 + k0),
                (__attribute__((address_space(3))) void*)&As[w * 32 + i * 8][0],
                16, 0, 0);
#pragma unroll
        for (int i = 0; i < 4; ++i)
            __builtin_amdgcn_global_load_lds(
                (const __attribute__((address_space(1))) void*)(
                    Bb + (size_t)(i * 8) * INP + k0),
                (__attribute__((address_space(3))) void*)&Bs[w * 32 + i * 8][0],
                16, 0, 0);
        __syncthreads();
#pragma unroll
        for (int kh = 0; kh < 2; ++kh) {
            const int slot = (kh * 4 + (l >> 4)) ^ (l & 7);
            bf16x8 af[4], bfr[4];
#pragma unroll
            for (int mt = 0; mt < 4; ++mt)
                af[mt] = As[wm * 64 + mt * 16 + (l & 15)][slot];
#pragma unroll
            for (int nt = 0; nt < 4; ++nt)
                bfr[nt] = Bs[wn * 64 + nt * 16 + (l & 15)][slot];
#pragma unroll
            for (int mt = 0; mt < 4; ++mt)
#pragma unroll
                for (int nt = 0; nt < 4; ++nt)
                    acc[mt][nt] = __builtin_amdgcn_mfma_f32_16x16x32_bf16(
                        af[mt], bfr[nt], acc[mt][nt], 0, 0, 0);
        }
        __syncthreads();
    }

    const int cr = (l >> 4) * 4, cc = l & 15;
#pragma unroll
    for (int mt = 0; mt < 4; ++mt) {
#pragma unroll
        for (int nt = 0; nt < 4; ++nt) {
            const int gc = wn * 64 + nt * 16 + cc;
            const float bv = C0s[bucket * 128 + gc];
#pragma unroll
            for (int r = 0; r < 4; ++r) {
                float val = acc[mt][nt][r] * 0.125f + bv;
                float mx = val;
                mx = fmaxf(mx, __shfl_xor(mx, 1, 64));
                mx = fmaxf(mx, __shfl_xor(mx, 2, 64));
                mx = fmaxf(mx, __shfl_xor(mx, 4, 64));
                mx = fmaxf(mx, __shfl_xor(mx, 8, 64));
                float e = expf(val - mx);
                e += __shfl_xor(e, 1, 64);
                e += __shfl_xor(e, 2, 64);
                e += __shfl_xor(e, 4, 64);
                e += __shfl_xor(e, 8, 64);
                const float lse = mx + logf(e);
                int rg = off + tile * 128 + wm * 64 + mt * 16 + cr + r;
                int orow = perm[rg < end ? rg : off];
                Csel[(size_t)orow * 128 + gc] = val - lse;
            }
        }
    }
}

// ---------------------------------------------------------------------------
// Layer-0 attend: weights = dsel log-probs (precomputed), v bf16.
// ---------------------------------------------------------------------------
__global__ __launch_bounds__(512) void attend0_k(
    const float* __restrict__ dsel, const ushort* __restrict__ vb,
    ushort* __restrict__ o)
{
    const int bt = blockIdx.x;
    const int l  = threadIdx.x & 63;
    const int h  = threadIdx.x >> 6;
    const int dg = l & 7, mg = l >> 3;

    const float w0 = dsel[(size_t)bt * 128 + h * 16 + mg];
    const float w1 = dsel[(size_t)bt * 128 + h * 16 + 8 + mg];

    const ushort* base = vb + (size_t)bt * ENW + h * 64 + dg * 8;
    uint4 v0 = *reinterpret_cast<const uint4*>(base + (size_t)mg * EDIM);
    uint4 v1 = *reinterpret_cast<const uint4*>(base + (size_t)(8 + mg) * EDIM);
    const ushort* u0 = reinterpret_cast<const ushort*>(&v0);
    const ushort* u1 = reinterpret_cast<const ushort*>(&v1);
    float acc[8];
#pragma unroll
    for (int j = 0; j < 8; ++j)
        acc[j] = w0 * bf2f(u0[j]) + w1 * bf2f(u1[j]);
#pragma unroll
    for (int off = 8; off < 64; off <<= 1)
#pragma unroll
        for (int j = 0; j < 8; ++j) acc[j] += __shfl_xor(acc[j], off, 64);

    if (mg == 0) {
        uint4 pk;
        pk.x = f2bf(acc[0]) | ((unsigned)f2bf(acc[1]) << 16);
        pk.y = f2bf(acc[2]) | ((unsigned)f2bf(acc[3]) << 16);
        pk.z = f2bf(acc[4]) | ((unsigned)f2bf(acc[5]) << 16);
        pk.w = f2bf(acc[6]) | ((unsigned)f2bf(acc[7]) << 16);
        *reinterpret_cast<uint4*>(o + (size_t)bt * EDIM + h * 64 + dg * 8) = pk;
    }
}

// ---------------------------------------------------------------------------
// Row LayerNorm over E=512: one wave per row; emits bf16 ONLY (r14).
// ---------------------------------------------------------------------------
__global__ __launch_bounds__(256) void ln_k(
    const float* __restrict__ x, const float* __restrict__ g,
    const float* __restrict__ b, ushort* __restrict__ yb)
{
    const int row = blockIdx.x * 4 + (threadIdx.x >> 6);
    const int lane = threadIdx.x & 63;
    const float* xr = x + (size_t)row * EDIM + lane * 8;
    float4 a0 = *reinterpret_cast<const float4*>(xr);
    float4 a1 = *reinterpret_cast<const float4*>(xr + 4);
    float v[8] = {a0.x, a0.y, a0.z, a0.w, a1.x, a1.y, a1.z, a1.w};

    float s = 0.f;
#pragma unroll
    for (int j = 0; j < 8; ++j) s += v[j];
#pragma unroll
    for (int off = 32; off; off >>= 1) s += __shfl_xor(s, off, 64);
    const float m = s * (1.f / 512.f);

    float q = 0.f;
#pragma unroll
    for (int j = 0; j < 8; ++j) { float d = v[j] - m; q = fmaf(d, d, q); }
#pragma unroll
    for (int off = 32; off; off >>= 1) q += __shfl_xor(q, off, 64);
    const float inv = rsqrtf(q * (1.f / 512.f) + 1e-5f);

    const int c = lane * 8;
    float4 g0 = *reinterpret_cast<const float4*>(g + c);
    float4 g1 = *reinterpret_cast<const float4*>(g + c + 4);
    float4 b0 = *reinterpret_cast<const float4*>(b + c);
    float4 b1 = *reinterpret_cast<const float4*>(b + c + 4);
    float gg[8] = {g0.x, g0.y, g0.z, g0.w, g1.x, g1.y, g1.z, g1.w};
    float bb[8] = {b0.x, b0.y, b0.z, b0.w, b1.x, b1.y, b1.z, b1.w};
    float out[8];
#pragma unroll
    for (int j = 0; j < 8; ++j) out[j] = (v[j] - m) * inv * gg[j] + bb[j];
    uint4 p;
    p.x = f2bf(out[0]) | ((unsigned)f2bf(out[1]) << 16);
    p.y = f2bf(out[2]) | ((unsigned)f2bf(out[3]) << 16);
    p.z = f2bf(out[4]) | ((unsigned)f2bf(out[5]) << 16);
    p.w = f2bf(out[6]) | ((unsigned)f2bf(out[7]) << 16);
    *reinterpret_cast<uint4*>(yb + (size_t)row * EDIM + c) = p;
}

// out[row] = x[row,:] . Wm + bm
__global__ __launch_bounds__(256) void final_k(
    const float* __restrict__ x, const float* __restrict__ Wm,
    const float* __restrict__ bm, float* __restrict__ out)
{
    const int row = blockIdx.x * 4 + (threadIdx.x >> 6);
    const int lane = threadIdx.x & 63;
    const float* xr = x + (size_t)row * EDIM + lane * 8;
    const float* wr = Wm + lane * 8;
    float s = 0.f;
#pragma unroll
    for (int j = 0; j < 8; ++j) s = fmaf(xr[j], wr[j], s);
#pragma unroll
    for (int off = 32; off; off >>= 1) s += __shfl_xor(s, off, 64);
    if (lane == 0) out[row] = s + bm[0];
}

// ---------------------------------------------------------------------------
extern "C" void kernel_launch(void* const* d_in, const int* in_sizes, int n_in,
                              void* d_out, int out_size, void* d_ws, size_t ws_size,
                              hipStream_t stream)
{
    (void)in_sizes; (void)n_in; (void)out_size; (void)ws_size;
    const float* features = (const float*)d_in[0];
    const int*   targets  = (const int*)d_in[1];
    const float* emb      = (const float*)d_in[2];
    const float* Wf       = (const float*)d_in[3];
    const float* bfv      = (const float*)d_in[4];
    const float* a0Wo     = (const float*)d_in[5];
    const float* a0bo     = (const float*)d_in[6];
    const float* Wm       = (const float*)d_in[7];
    const float* bm       = (const float*)d_in[8];
    const float *ffg[3], *ffb[3], *W1[3], *b1[3], *W2[3], *b2[3];
    for (int i = 0; i < 3; ++i) {
        ffg[i] = (const float*)d_in[9 + 6 * i];
        ffb[i] = (const float*)d_in[10 + 6 * i];
        W1[i]  = (const float*)d_in[11 + 6 * i];
        b1[i]  = (const float*)d_in[12 + 6 * i];
        W2[i]  = (const float*)d_in[13 + 6 * i];
        b2[i]  = (const float*)d_in[14 + 6 * i];
    }
    const float *ag[2], *abp[2], *aWqkv[2], *aWo[2], *abo[2];
    for (int i = 0; i < 2; ++i) {
        ag[i]    = (const float*)d_in[27 + 5 * i];
        abp[i]   = (const float*)d_in[28 + 5 * i];
        aWqkv[i] = (const float*)d_in[29 + 5 * i];
        aWo[i]   = (const float*)d_in[30 + 5 * i];
        abo[i]   = (const float*)d_in[31 + 5 * i];
    }

    // ---- workspace carve-up ----
    char* wsc = (char*)d_ws;
    auto alloc = [&](size_t bytes) { char* p = wsc; wsc += bytes; return p; };
    ushort* WfvT  = (ushort*)alloc((size_t)ENW * INP * 2);       // 25.2 MB
    ushort* BTg   = (ushort*)alloc((size_t)NDOT * INP * 2);      // 6.3 MB
    float*  C0s   = (float*) alloc((size_t)NDOT * 4);
    float*  dsel  = (float*) alloc((size_t)BTOT * 128 * 4);      // 2.1 MB
    int*    perm  = (int*)   alloc((size_t)BTOT * 4);
    int*    boff  = (int*)   alloc(32 * 4);
    ushort* a0WoT = (ushort*)alloc((size_t)EDIM * EDIM * 2);
    ushort *W1T[3], *W2T[3], *WoT[2], *Wv_bf[2], *WcombT[2];
    for (int i = 0; i < 3; ++i) {
        W1T[i] = (ushort*)alloc((size_t)FFH * EDIM * 2);
        W2T[i] = (ushort*)alloc((size_t)EDIM * FFH * 2);
    }
    for (int i = 0; i < 2; ++i) {
        WoT[i]    = (ushort*)alloc((size_t)EDIM * EDIM * 2);
        Wv_bf[i]  = (ushort*)alloc((size_t)EDIM * EDIM * 2);
        WcombT[i] = (ushort*)alloc((size_t)EDIM * EDIM * 2);
    }
    ushort* featb = (ushort*)alloc((size_t)BTOT * INP * 2);      // 12.6 MB
    ushort* o_b   = (ushort*)alloc((size_t)BTOT * EDIM * 2);     // 4.2 MB
    float*  x     = (float*) alloc((size_t)BTOT * EDIM * 4);     // 8.4 MB
    ushort* xlnb  = (ushort*)alloc((size_t)BTOT * EDIM * 2);
    ushort* hb    = (ushort*)alloc((size_t)BTOT * FFH * 2);      // 8.4 MB
    ushort* vb    = (ushort*)alloc((size_t)BTOT * ENW * 2);      // 67 MB

    const dim3 blk(256, 1, 1);

    // ---- prep: 3 separate dispatches (r8 structure — measured faster) ----
    conv_all_k<<<3328, blk, 0, stream>>>(features, featb,
                                         aWqkv[0], aWqkv[1], Wv_bf[0], Wv_bf[1]);
    gproj_k<<<dim3(128, 9), blk, 0, stream>>>(Wf, bfv, emb, BTg, C0s,
                                              targets, perm, boff);

    TJobs tj;
    int ob = 0, ji = 0;
    auto addj = [&](const float* in, ushort* out, int ld, int c0, int R,
                    int gbx, int gby) {
        tj.j[ji++] = {in, out, ld, c0, R, gbx, ob};
        ob += gbx * gby;
    };
    addj(Wf, WfvT, KVW, ENW, INP, 128, 24);       // v-half of Wf (3072 blocks)
    addj(a0Wo, a0WoT, EDIM, 0, EDIM, 8, 8);
    for (int i = 0; i < 3; ++i) {
        addj(W1[i], W1T[i], FFH, 0, EDIM, 16, 8);
        addj(W2[i], W2T[i], EDIM, 0, FFH, 8, 16);
    }
    addj(aWo[0], WoT[0], EDIM, 0, EDIM, 8, 8);
    addj(aWo[1], WoT[1], EDIM, 0, EDIM, 8, 8);
    transpose_all_k<<<ob, blk, 0, stream>>>(tj);

    // ---- layer 0 ----
    const float CATT = -44.36141955583650f;   // -16*ln(16)
    gemm_dots_k<<<dim3(32, 16), blk, 0, stream>>>(featb, BTg, perm, boff,
                                                  C0s, dsel);
    for (int i = 0; i < 2; ++i)
        gemm_mfma_k<64, 128, 32, 64, 4, false, true>
            <<<dim3(EDIM / 128, EDIM / 64), blk, 0, stream>>>(
            WoT[i], EDIM, Wv_bf[i], EDIM, WcombT[i], EDIM, EDIM,
            nullptr, nullptr, 0, CATT);
    gemm_v256_k<<<dim3(ENW / 256, BTOT / 256), dim3(512, 1, 1), 0, stream>>>(
        featb, WfvT, bfv + ENW, vb);
    attend0_k<<<BTOT, 512, 0, stream>>>(dsel, vb, o_b);
    gemm_pipe64_k<false, false>
        <<<dim3(EDIM / 128, BTOT / 64), blk, 0, stream>>>(
        o_b, EDIM, a0WoT, EDIM, x, EDIM, EDIM, a0bo, nullptr, 0, 1.f);

    auto ln = [&](const float* g, const float* b) {
        ln_k<<<BTOT / 4, blk, 0, stream>>>(x, g, b, xlnb);
    };
    auto ff = [&](int i) {
        ln(ffg[i], ffb[i]);
        gemm_pipe64_k<true, true>
            <<<dim3(FFH / 128, BTOT / 64), blk, 0, stream>>>(
            xlnb, EDIM, W1T[i], EDIM, hb, FFH, EDIM, b1[i], nullptr, 0, 1.f);
        gemm_pipe64_k<false, false>
            <<<dim3(EDIM / 128, BTOT / 64), blk, 0, stream>>>(
            hb, FFH, W2T[i], FFH, x, EDIM, FFH, b2[i], xlnb, EDIM, 1.f);
    };
    auto attn = [&](int i) {
        ln(ag[i], abp[i]);
        gemm_pipe64_k<false, false>
            <<<dim3(EDIM / 128, BTOT / 64), blk, 0, stream>>>(
            xlnb, EDIM, WcombT[i], EDIM, x, EDIM, EDIM, abo[i], xlnb, EDIM, 1.f);
    };

    ff(0);
    attn(0);
    ff(1);
    attn(1);
    ff(2);

    final_k<<<BTOT / 4, blk, 0, stream>>>(x, Wm, bm, (float*)d_out);
}

// Round 18
// 404.772 us; speedup vs baseline: 1.2413x; 1.0214x over previous
//
#include <hip/hip_runtime.h>
#include <math.h>

// MixedHead: B=16,T=256 -> BT=4096; INP=1536; E=512; H=8; N=16; D=64.
#define BTOT 4096
#define INP  1536
#define EDIM 512
#define NTOK 16
#define KVW  16384   // 2*E*N
#define ENW  8192    // E*N
#define FFH  1024    // 2*E
#define NDOT 2048    // 16 targets x 128 (h,m)

typedef __attribute__((ext_vector_type(8))) __bf16 bf16x8;
typedef __attribute__((ext_vector_type(4))) float f32x4;

__device__ __forceinline__ ushort f2bf(float f) {
    union { float f; unsigned u; } v; v.f = f;
    unsigned r = v.u + 0x7fffu + ((v.u >> 16) & 1u);
    return (ushort)(r >> 16);
}
__device__ __forceinline__ float bf2f(ushort h) {
    union { unsigned u; float f; } v; v.u = ((unsigned)h) << 16;
    return v.f;
}

// ---------------------------------------------------------------------------
// Transpose f32 [R][ld] (cols c0..) -> bf16 [C][R]. 10 jobs, one launch (r8).
// ---------------------------------------------------------------------------
__device__ __forceinline__ void transpose_body(
    const float* in, int ld, int c0, int R, ushort* out,
    int bx, int by, int tid)
{
    __shared__ float t[64][65];
    const int bc = bx * 64 + c0;
    const int br = by * 64;
#pragma unroll
    for (int it = 0; it < 16; ++it) {
        int idx = tid + it * 256;
        int r = idx >> 6, c = idx & 63;
        t[r][c] = in[(size_t)(br + r) * ld + bc + c];
    }
    __syncthreads();
    const int C0 = bx * 64;
#pragma unroll
    for (int it = 0; it < 4; ++it) {
        int idx = tid + it * 256;          // 1024 = 64 cols x 16 row-quads
        int cc = idx >> 4, rp = idx & 15;
        uint2 w2;
        w2.x = f2bf(t[4 * rp + 0][cc]) | ((unsigned)f2bf(t[4 * rp + 1][cc]) << 16);
        w2.y = f2bf(t[4 * rp + 2][cc]) | ((unsigned)f2bf(t[4 * rp + 3][cc]) << 16);
        *reinterpret_cast<uint2*>(out + (size_t)(C0 + cc) * R + br + 4 * rp) = w2;
    }
}

struct TJob { const float* in; ushort* out; int ld, c0, R, gbx, boffs; };
struct TJobs { TJob j[10]; };

__global__ __launch_bounds__(256) void transpose_all_k(TJobs jobs)
{
    const int b = blockIdx.x;
    int ji = 0;
    while (ji < 9 && b >= jobs.j[ji + 1].boffs) ++ji;
    TJob jb = jobs.j[ji];
    const int rel = b - jb.boffs;
    transpose_body(jb.in, jb.ld, jb.c0, jb.R, jb.out,
                   rel % jb.gbx, rel / jb.gbx, threadIdx.x);
}

// ---------------------------------------------------------------------------
// Merged converts (r8): [0,3072) features->bf16; [3072,3328) Wqkv v-slices.
// ---------------------------------------------------------------------------
__global__ __launch_bounds__(256) void conv_all_k(
    const float* __restrict__ features, ushort* __restrict__ featb,
    const float* __restrict__ wq0, const float* __restrict__ wq1,
    ushort* __restrict__ wv0, ushort* __restrict__ wv1)
{
    const int b = blockIdx.x;
    if (b < 3072) {
        const int i = b * 256 + threadIdx.x;          // < 786432
        const float4* p = reinterpret_cast<const float4*>(features) + 2 * (size_t)i;
        float4 a = p[0], c = p[1];
        uint4 o;
        o.x = f2bf(a.x) | ((unsigned)f2bf(a.y) << 16);
        o.y = f2bf(a.z) | ((unsigned)f2bf(a.w) << 16);
        o.z = f2bf(c.x) | ((unsigned)f2bf(c.y) << 16);
        o.w = f2bf(c.z) | ((unsigned)f2bf(c.w) << 16);
        reinterpret_cast<uint4*>(featb)[i] = o;
    } else {
        const int bb = b - 3072;
        const float* src = (bb >= 128) ? wq1 : wq0;
        ushort* dst = (bb >= 128) ? wv1 : wv0;
        const int idx = (bb & 127) * 256 + threadIdx.x;   // < 32768
        const int row = idx >> 6, c8 = (idx & 63) * 8;
        const float4* p = reinterpret_cast<const float4*>(
            src + (size_t)row * (3 * EDIM) + 2 * EDIM + c8);
        float4 a = p[0], c = p[1];
        uint4 o;
        o.x = f2bf(a.x) | ((unsigned)f2bf(a.y) << 16);
        o.y = f2bf(a.z) | ((unsigned)f2bf(a.w) << 16);
        o.z = f2bf(c.x) | ((unsigned)f2bf(c.y) << 16);
        o.w = f2bf(c.z) | ((unsigned)f2bf(c.w) << 16);
        *reinterpret_cast<uint4*>(dst + (size_t)row * EDIM + c8) = o;
    }
}

// ---------------------------------------------------------------------------
// G projection + embedded targets counting sort (r8, grid (128,9)).
// ---------------------------------------------------------------------------
__global__ __launch_bounds__(256) void gproj_k(
    const float* __restrict__ Wf, const float* __restrict__ bfv,
    const float* __restrict__ emb, ushort* __restrict__ BTg,
    float* __restrict__ C0s, const int* __restrict__ targets,
    int* __restrict__ perm, int* __restrict__ boff)
{
    if (blockIdx.y == 8) {
        if (blockIdx.x != 0) return;
        __shared__ int cnt[NTOK], off_s[NTOK], cur[NTOK];
        const int tid = threadIdx.x;
        if (tid < NTOK) cnt[tid] = 0;
        __syncthreads();
        for (int i = tid; i < BTOT; i += 256) atomicAdd(&cnt[targets[i]], 1);
        __syncthreads();
        if (tid == 0) {
            int s = 0;
            for (int b = 0; b < NTOK; ++b) { off_s[b] = s; cur[b] = s; s += cnt[b]; }
            for (int b = 0; b < NTOK; ++b) boff[b] = off_s[b];
            boff[NTOK] = s;
        }
        __syncthreads();
        for (int i = tid; i < BTOT; i += 256) {
            int t = targets[i];
            int p = atomicAdd(&cur[t], 1);
            perm[p] = i;
        }
        return;
    }

    const int hm = blockIdx.x;           // h*16 + m
    const int h = hm >> 4, m = hm & 15;
    const int l = threadIdx.x & 63, w = threadIdx.x >> 6;
    const int t = l & 15, isub = l >> 4;
    const int colb = m * 512 + h * 64;
    const int ibase = blockIdx.y * (INP / 8);

    float4 e[16];
#pragma unroll
    for (int q = 0; q < 16; ++q)
        e[q] = *reinterpret_cast<const float4*>(emb + t * EDIM + h * 64 + q * 4);

    const int n = t * 128 + hm;
    for (int i0 = ibase; i0 < ibase + INP / 8; i0 += 16) {
        const int i = i0 + w * 4 + isub;
        const float* wr = Wf + (size_t)i * KVW + colb;
        float acc = 0.f;
#pragma unroll
        for (int q = 0; q < 16; ++q) {
            float4 v4 = *reinterpret_cast<const float4*>(wr + q * 4);
            acc = fmaf(v4.x, e[q].x, fmaf(v4.y, e[q].y,
                  fmaf(v4.z, e[q].z, fmaf(v4.w, e[q].w, acc))));
        }
        BTg[(size_t)n * INP + i] = f2bf(acc);
    }
    if (blockIdx.y == 0 && w == 0 && isub == 0) {
        const float* br = bfv + colb;
        float acc = 0.f;
#pragma unroll
        for (int q = 0; q < 16; ++q) {
            float4 v4 = *reinterpret_cast<const float4*>(br + q * 4);
            acc = fmaf(v4.x, e[q].x, fmaf(v4.y, e[q].y,
                  fmaf(v4.z, e[q].z, fmaf(v4.w, e[q].w, acc))));
        }
        C0s[n] = 0.125f * acc;
    }
}

// ---------------------------------------------------------------------------
// 64x128 barrier-minimal pipelined layer GEMM (r17, proven: -21 us).
// 4 waves (2x2 of 32x64), LDS 48 KB -> 3 blocks/CU. Bit-identical K-order /
// epilogue to the old gemm_mfma_k<64,128,32,64,4>.
// ---------------------------------------------------------------------------
template <bool GELU, bool OUTBF>
__global__ __launch_bounds__(256, 3) void gemm_pipe64_k(
    const ushort* __restrict__ A, int lda,
    const ushort* __restrict__ BT, int ldb,
    void* __restrict__ Cp, int ldc, int K,
    const float* __restrict__ bias,
    const ushort* __restrict__ res, int ldr,
    float scale)
{
    __shared__ bf16x8 Asl[2][64][8];
    __shared__ bf16x8 Bsl[2][128][8];
    const int tid = threadIdx.x;
    const int l = tid & 63, w = tid >> 6;
    const int wm = w >> 1, wn = w & 1;      // 2 x 2 waves of 32x64
    const int brow = blockIdx.y * 64, bcol = blockIdx.x * 128;
    const int lr = l >> 3, ls = (l & 7) ^ lr;

    const ushort* Ab = A  + (size_t)(brow + w * 16 + lr) * lda + ls * 8;
    const ushort* Bb = BT + (size_t)(bcol + w * 32 + lr) * ldb + ls * 8;

#define STAGE_P(d, t) do { const int k0s = (t) * 64;                          \
    _Pragma("unroll")                                                          \
    for (int g = 0; g < 2; ++g)                                                \
        __builtin_amdgcn_global_load_lds(                                      \
            (const __attribute__((address_space(1))) void*)(Ab + (size_t)(g * 8) * lda + k0s), \
            (__attribute__((address_space(3))) void*)&Asl[d][w * 16 + g * 8][0], 16, 0, 0);    \
    _Pragma("unroll")                                                          \
    for (int g = 0; g < 4; ++g)                                                \
        __builtin_amdgcn_global_load_lds(                                      \
            (const __attribute__((address_space(1))) void*)(Bb + (size_t)(g * 8) * ldb + k0s), \
            (__attribute__((address_space(3))) void*)&Bsl[d][w * 32 + g * 8][0], 16, 0, 0);    \
} while (0)

#define RD_AP(dst, dd, kh) do {                                                \
    const int slot_ = ((kh) * 4 + (l >> 4)) ^ (l & 7);                         \
    _Pragma("unroll")                                                          \
    for (int mt = 0; mt < 2; ++mt)                                             \
        dst[mt] = Asl[dd][wm * 32 + mt * 16 + (l & 15)][slot_];                \
} while (0)

#define RD_BP(dd, kh) do {                                                     \
    const int slot_ = ((kh) * 4 + (l >> 4)) ^ (l & 7);                         \
    _Pragma("unroll")                                                          \
    for (int nt = 0; nt < 4; ++nt)                                             \
        bfr[nt][kh] = Bsl[dd][wn * 64 + nt * 16 + (l & 15)][slot_];            \
} while (0)

#define MFMA_P(af, kh) do {                                                    \
    __builtin_amdgcn_s_setprio(1);                                             \
    _Pragma("unroll")                                                          \
    for (int mt = 0; mt < 2; ++mt)                                             \
        _Pragma("unroll")                                                      \
        for (int nt = 0; nt < 4; ++nt)                                         \
            acc[mt][nt] = __builtin_amdgcn_mfma_f32_16x16x32_bf16(             \
                af[mt], bfr[nt][kh], acc[mt][nt], 0, 0, 0);                    \
    __builtin_amdgcn_s_setprio(0);                                             \
} while (0)

    f32x4 acc[2][4];
#pragma unroll
    for (int i = 0; i < 2; ++i)
#pragma unroll
        for (int j = 0; j < 4; ++j) acc[i][j] = (f32x4)0.f;

    // prologue: tiles 0 and 1 in flight (6 loads each); wait tile 0 only.
    STAGE_P(0, 0);
    STAGE_P(1, 1);
    asm volatile("s_waitcnt vmcnt(6)" ::: "memory");
    __builtin_amdgcn_s_barrier();

    bf16x8 aA[2], aB[2], bfr[4][2];
    RD_AP(aA, 0, 0);
    RD_BP(0, 0);

    const int NT = K / 64;
    for (int j = 0; j < NT; ++j) {
        const int d = j & 1;
        if (j > 0 && j + 1 < NT) STAGE_P(d ^ 1, j + 1);
        RD_AP(aB, d, 1);
        RD_BP(d, 1);
        MFMA_P(aA, 0);
        MFMA_P(aB, 1);
        __syncthreads();            // vmcnt(0)+lgkmcnt(0) drain: tile j+1
                                    // staged, all waves done with buffer d
        if (j + 1 < NT) {
            RD_AP(aA, d ^ 1, 0);
            RD_BP(d ^ 1, 0);
        }
    }
#undef STAGE_P
#undef RD_AP
#undef RD_BP
#undef MFMA_P

    const int cr = (l >> 4) * 4, cc = l & 15;
#pragma unroll
    for (int mt = 0; mt < 2; ++mt) {
#pragma unroll
        for (int nt = 0; nt < 4; ++nt) {
            const int gc = bcol + wn * 64 + nt * 16 + cc;
            const float bv = bias ? bias[gc] : 0.f;
#pragma unroll
            for (int r = 0; r < 4; ++r) {
                const size_t gr = (size_t)brow + wm * 32 + mt * 16 + cr + r;
                float v = acc[mt][nt][r] * scale + bv;
                if (GELU) v = 0.5f * v * (1.f + erff(v * 0.70710678118654752f));
                if (res) v += bf2f(res[gr * ldr + gc]);
                if (OUTBF) ((ushort*)Cp)[gr * ldc + gc] = f2bf(v);
                else       ((float*)Cp)[gr * ldc + gc]  = v;
            }
        }
    }
}

// ---------------------------------------------------------------------------
// 256x256 v-GEMM, barrier-minimal pipeline, plain 2-D grid (r13/r14, proven).
// ---------------------------------------------------------------------------
__global__ __launch_bounds__(512, 2) void gemm_v256_k(
    const ushort* __restrict__ A,        // featb [BTOT][INP]
    const ushort* __restrict__ BT,       // WfvT [ENW][INP]
    const float* __restrict__ bias,      // bfv + ENW
    ushort* __restrict__ C)              // vb [BTOT][ENW]
{
    __shared__ bf16x8 lds[2][2][256][8];   // [dbuf][A/B][row][16B chunk]
    const int tid = threadIdx.x;
    const int l = tid & 63, w = tid >> 6;
    const int wm = w >> 2, wn = w & 3;      // 2 x 4 wave grid
    const int brow = blockIdx.y * 256, bcol = blockIdx.x * 256;
    const int lr = l >> 3, ls = (l & 7) ^ lr;

    const ushort* Ab = A  + (size_t)(brow + w * 8 + lr) * INP + ls * 8;
    const ushort* Bb = BT + (size_t)(bcol + w * 8 + lr) * INP + ls * 8;

#define STAGE_T(d, t) do { const int k0s = (t) * 64;                          \
    _Pragma("unroll")                                                          \
    for (int g = 0; g < 4; ++g)                                                \
        __builtin_amdgcn_global_load_lds(                                      \
            (const __attribute__((address_space(1))) void*)(Ab + (size_t)(g * 64) * INP + k0s), \
            (__attribute__((address_space(3))) void*)&lds[d][0][g * 64 + w * 8][0], 16, 0, 0);  \
    _Pragma("unroll")                                                          \
    for (int g = 0; g < 4; ++g)                                                \
        __builtin_amdgcn_global_load_lds(                                      \
            (const __attribute__((address_space(1))) void*)(Bb + (size_t)(g * 64) * INP + k0s), \
            (__attribute__((address_space(3))) void*)&lds[d][1][g * 64 + w * 8][0], 16, 0, 0);  \
} while (0)

#define RD_A(dst, dd, rh, kh) do {                                             \
    const int slot_ = ((kh) * 4 + (l >> 4)) ^ (l & 7);                         \
    _Pragma("unroll")                                                          \
    for (int mt = 0; mt < 4; ++mt)                                             \
        dst[mt] = lds[dd][0][wm * 128 + (rh) * 64 + mt * 16 + (l & 15)][slot_]; \
} while (0)

#define RD_B(dd, kh) do {                                                      \
    const int slot_ = ((kh) * 4 + (l >> 4)) ^ (l & 7);                         \
    _Pragma("unroll")                                                          \
    for (int nt = 0; nt < 4; ++nt)                                             \
        bfr[nt][kh] = lds[dd][1][wn * 64 + nt * 16 + (l & 15)][slot_];         \
} while (0)

#define MFMA4(base, af, kh) do {                                               \
    __builtin_amdgcn_s_setprio(1);                                             \
    _Pragma("unroll")                                                          \
    for (int mt = 0; mt < 4; ++mt)                                             \
        _Pragma("unroll")                                                      \
        for (int nt = 0; nt < 4; ++nt)                                         \
            acc[(base) + mt][nt] = __builtin_amdgcn_mfma_f32_16x16x32_bf16(    \
                af[mt], bfr[nt][kh], acc[(base) + mt][nt], 0, 0, 0);           \
    __builtin_amdgcn_s_setprio(0);                                             \
} while (0)

    f32x4 acc[8][4];
#pragma unroll
    for (int i = 0; i < 8; ++i)
#pragma unroll
        for (int j = 0; j < 4; ++j) acc[i][j] = (f32x4)0.f;

    // prologue: tiles 0 and 1 in flight; wait tile 0 only.
    STAGE_T(0, 0);
    STAGE_T(1, 1);
    asm volatile("s_waitcnt vmcnt(8)" ::: "memory");
    __builtin_amdgcn_s_barrier();

    bf16x8 aA[4], aB[4], bfr[4][2];
    RD_A(aA, 0, 0, 0);
    RD_B(0, 0);

    const int NT = INP / 64;   // 24
    for (int j = 0; j < NT; ++j) {
        const int d = j & 1;
        if (j > 0 && j + 1 < NT) STAGE_T(d ^ 1, j + 1);
        RD_A(aB, d, 0, 1);          // phase-1 frags
        RD_B(d, 1);
        MFMA4(0, aA, 0);            // phase 0 (rh0,kh0)
        RD_A(aA, d, 1, 0);          // phase-2 frags
        MFMA4(0, aB, 1);            // phase 1 (rh0,kh1)
        RD_A(aB, d, 1, 1);          // phase-3 frags
        MFMA4(4, aA, 0);            // phase 2 (rh1,kh0)
        MFMA4(4, aB, 1);            // phase 3 (rh1,kh1)
        __syncthreads();            // drains vmcnt(0): tile j+1 staged + all
                                    // waves done reading buffer d
        if (j + 1 < NT) {           // pre-issue next tile's phase-0 frags
            RD_A(aA, d ^ 1, 0, 0);
            RD_B(d ^ 1, 0);
        }
    }
#undef STAGE_T
#undef RD_A
#undef RD_B
#undef MFMA4

    const int cr = (l >> 4) * 4, cc = l & 15;
#pragma unroll
    for (int h = 0; h < 2; ++h)
#pragma unroll
        for (int mt = 0; mt < 4; ++mt)
#pragma unroll
            for (int nt = 0; nt < 4; ++nt) {
                const int gc = bcol + wn * 64 + nt * 16 + cc;
                const float bv = bias[gc];
#pragma unroll
                for (int r = 0; r < 4; ++r) {
                    const size_t gr = (size_t)brow + wm * 128 + h * 64 + mt * 16 + cr + r;
                    C[gr * ENW + gc] = f2bf(acc[h * 4 + mt][nt][r] + bv);
                }
            }
}

// ---------------------------------------------------------------------------
// Bucketed dots GEMM + log-softmax epilogue, NOW barrier-minimal pipelined
// (same proven schedule; staging->inactive buffer, one __syncthreads/K-tile,
// frags pre-issued; perm-indirected A staging unchanged; accumulation order
// identical to the 2-barrier version -> bit-identical output).
// ---------------------------------------------------------------------------
__global__ __launch_bounds__(256, 2) void gemm_dots_k(
    const ushort* __restrict__ A,
    const ushort* __restrict__ BT,
    const int* __restrict__ perm, const int* __restrict__ boff,
    const float* __restrict__ C0s, float* __restrict__ Csel)
{
    const int bucket = blockIdx.y;
    const int off = boff[bucket], end = boff[bucket + 1];
    const int tile = blockIdx.x;
    if (tile * 128 >= end - off) return;

    __shared__ bf16x8 Asl[2][128][8];
    __shared__ bf16x8 Bsl[2][128][8];
    const int tid = threadIdx.x;
    const int l = tid & 63, w = tid >> 6;
    const int wm = w >> 1, wn = w & 1;
    const int lr = l >> 3;
    const int ls = (l & 7) ^ lr;

    const ushort* Asrc[4];
#pragma unroll
    for (int i = 0; i < 4; ++i) {
        int rg = off + tile * 128 + w * 32 + lr + i * 8;
        Asrc[i] = A + (size_t)perm[rg < end ? rg : off] * INP + ls * 8;
    }
    const ushort* Bb = BT + (size_t)(bucket * 128 + w * 32 + lr) * INP + ls * 8;

#define DSTAGE(d, t) do { const int k0s = (t) * 64;                           \
    _Pragma("unroll")                                                          \
    for (int g = 0; g < 4; ++g)                                                \
        __builtin_amdgcn_global_load_lds(                                      \
            (const __attribute__((address_space(1))) void*)(Asrc[g] + k0s),    \
            (__attribute__((address_space(3))) void*)&Asl[d][w * 32 + g * 8][0], 16, 0, 0);    \
    _Pragma("unroll")                                                          \
    for (int g = 0; g < 4; ++g)                                                \
        __builtin_amdgcn_global_load_lds(                                      \
            (const __attribute__((address_space(1))) void*)(Bb + (size_t)(g * 8) * INP + k0s), \
            (__attribute__((address_space(3))) void*)&Bsl[d][w * 32 + g * 8][0], 16, 0, 0);    \
} while (0)

#define DRD_A(dst, dd, kh) do {                                                \
    const int slot_ = ((kh) * 4 + (l >> 4)) ^ (l & 7);                         \
    _Pragma("unroll")                                                          \
    for (int mt = 0; mt < 4; ++mt)                                             \
        dst[mt] = Asl[dd][wm * 64 + mt * 16 + (l & 15)][slot_];                \
} while (0)

#define DRD_B(dd, kh) do {                                                     \
    const int slot_ = ((kh) * 4 + (l >> 4)) ^ (l & 7);                         \
    _Pragma("unroll")                                                          \
    for (int nt = 0; nt < 4; ++nt)                                             \
        bfr[nt][kh] = Bsl[dd][wn * 64 + nt * 16 + (l & 15)][slot_];            \
} while (0)

#define DMFMA(af, kh) do {                                                     \
    __builtin_amdgcn_s_setprio(1);                                             \
    _Pragma("unroll")                                                          \
    for (int mt = 0; mt < 4; ++mt)                                             \
        _Pragma("unroll")                                                      \
        for (int nt = 0; nt < 4; ++nt)                                         \
            acc[mt][nt] = __builtin_amdgcn_mfma_f32_16x16x32_bf16(             \
                af[mt], bfr[nt][kh], acc[mt][nt], 0, 0, 0);                    \
    __builtin_amdgcn_s_setprio(0);                                             \
} while (0)

    f32x4 acc[4][4];
#pragma unroll
    for (int i = 0; i < 4; ++i)
#pragma unroll
        for (int j = 0; j < 4; ++j) acc[i][j] = (f32x4)0.f;

    DSTAGE(0, 0);
    DSTAGE(1, 1);
    asm volatile("s_waitcnt vmcnt(8)" ::: "memory");
    __builtin_amdgcn_s_barrier();

    bf16x8 aA[4], aB[4], bfr[4][2];
    DRD_A(aA, 0, 0);
    DRD_B(0, 0);

    const int NT = INP / 64;   // 24
    for (int j = 0; j < NT; ++j) {
        const int d = j & 1;
        if (j > 0 && j + 1 < NT) DSTAGE(d ^ 1, j + 1);
        DRD_A(aB, d, 1);
        DRD_B(d, 1);
        DMFMA(aA, 0);
        DMFMA(aB, 1);
        __syncthreads();
        if (j + 1 < NT) {
            DRD_A(aA, d ^ 1, 0);
            DRD_B(d ^ 1, 0);
        }
    }
#undef DSTAGE
#undef DRD_A
#undef DRD_B
#undef DMFMA

    const int cr = (l >> 4) * 4, cc = l & 15;
#pragma unroll
    for (int mt = 0; mt < 4; ++mt) {
#pragma unroll
        for (int nt = 0; nt < 4; ++nt) {
            const int gc = wn * 64 + nt * 16 + cc;
            const float bv = C0s[bucket * 128 + gc];
#pragma unroll
            for (int r = 0; r < 4; ++r) {
                float val = acc[mt][nt][r] * 0.125f + bv;
                float mx = val;
                mx = fmaxf(mx, __shfl_xor(mx, 1, 64));
                mx = fmaxf(mx, __shfl_xor(mx, 2, 64));
                mx = fmaxf(mx, __shfl_xor(mx, 4, 64));
                mx = fmaxf(mx, __shfl_xor(mx, 8, 64));
                float e = expf(val - mx);
                e += __shfl_xor(e, 1, 64);
                e += __shfl_xor(e, 2, 64);
                e += __shfl_xor(e, 4, 64);
                e += __shfl_xor(e, 8, 64);
                const float lse = mx + logf(e);
                int rg = off + tile * 128 + wm * 64 + mt * 16 + cr + r;
                int orow = perm[rg < end ? rg : off];
                Csel[(size_t)orow * 128 + gc] = val - lse;
            }
        }
    }
}

// ---------------------------------------------------------------------------
// Layer-0 attend: weights = dsel log-probs (precomputed), v bf16.
// ---------------------------------------------------------------------------
__global__ __launch_bounds__(512) void attend0_k(
    const float* __restrict__ dsel, const ushort* __restrict__ vb,
    ushort* __restrict__ o)
{
    const int bt = blockIdx.x;
    const int l  = threadIdx.x & 63;
    const int h  = threadIdx.x >> 6;
    const int dg = l & 7, mg = l >> 3;

    const float w0 = dsel[(size_t)bt * 128 + h * 16 + mg];
    const float w1 = dsel[(size_t)bt * 128 + h * 16 + 8 + mg];

    const ushort* base = vb + (size_t)bt * ENW + h * 64 + dg * 8;
    uint4 v0 = *reinterpret_cast<const uint4*>(base + (size_t)mg * EDIM);
    uint4 v1 = *reinterpret_cast<const uint4*>(base + (size_t)(8 + mg) * EDIM);
    const ushort* u0 = reinterpret_cast<const ushort*>(&v0);
    const ushort* u1 = reinterpret_cast<const ushort*>(&v1);
    float acc[8];
#pragma unroll
    for (int j = 0; j < 8; ++j)
        acc[j] = w0 * bf2f(u0[j]) + w1 * bf2f(u1[j]);
#pragma unroll
    for (int off = 8; off < 64; off <<= 1)
#pragma unroll
        for (int j = 0; j < 8; ++j) acc[j] += __shfl_xor(acc[j], off, 64);

    if (mg == 0) {
        uint4 pk;
        pk.x = f2bf(acc[0]) | ((unsigned)f2bf(acc[1]) << 16);
        pk.y = f2bf(acc[2]) | ((unsigned)f2bf(acc[3]) << 16);
        pk.z = f2bf(acc[4]) | ((unsigned)f2bf(acc[5]) << 16);
        pk.w = f2bf(acc[6]) | ((unsigned)f2bf(acc[7]) << 16);
        *reinterpret_cast<uint4*>(o + (size_t)bt * EDIM + h * 64 + dg * 8) = pk;
    }
}

// ---------------------------------------------------------------------------
// Row LayerNorm over E=512: one wave per row; emits bf16 ONLY (r14).
// ---------------------------------------------------------------------------
__global__ __launch_bounds__(256) void ln_k(
    const float* __restrict__ x, const float* __restrict__ g,
    const float* __restrict__ b, ushort* __restrict__ yb)
{
    const int row = blockIdx.x * 4 + (threadIdx.x >> 6);
    const int lane = threadIdx.x & 63;
    const float* xr = x + (size_t)row * EDIM + lane * 8;
    float4 a0 = *reinterpret_cast<const float4*>(xr);
    float4 a1 = *reinterpret_cast<const float4*>(xr + 4);
    float v[8] = {a0.x, a0.y, a0.z, a0.w, a1.x, a1.y, a1.z, a1.w};

    float s = 0.f;
#pragma unroll
    for (int j = 0; j < 8; ++j) s += v[j];
#pragma unroll
    for (int off = 32; off; off >>= 1) s += __shfl_xor(s, off, 64);
    const float m = s * (1.f / 512.f);

    float q = 0.f;
#pragma unroll
    for (int j = 0; j < 8; ++j) { float d = v[j] - m; q = fmaf(d, d, q); }
#pragma unroll
    for (int off = 32; off; off >>= 1) q += __shfl_xor(q, off, 64);
    const float inv = rsqrtf(q * (1.f / 512.f) + 1e-5f);

    const int c = lane * 8;
    float4 g0 = *reinterpret_cast<const float4*>(g + c);
    float4 g1 = *reinterpret_cast<const float4*>(g + c + 4);
    float4 b0 = *reinterpret_cast<const float4*>(b + c);
    float4 b1 = *reinterpret_cast<const float4*>(b + c + 4);
    float gg[8] = {g0.x, g0.y, g0.z, g0.w, g1.x, g1.y, g1.z, g1.w};
    float bb[8] = {b0.x, b0.y, b0.z, b0.w, b1.x, b1.y, b1.z, b1.w};
    float out[8];
#pragma unroll
    for (int j = 0; j < 8; ++j) out[j] = (v[j] - m) * inv * gg[j] + bb[j];
    uint4 p;
    p.x = f2bf(out[0]) | ((unsigned)f2bf(out[1]) << 16);
    p.y = f2bf(out[2]) | ((unsigned)f2bf(out[3]) << 16);
    p.z = f2bf(out[4]) | ((unsigned)f2bf(out[5]) << 16);
    p.w = f2bf(out[6]) | ((unsigned)f2bf(out[7]) << 16);
    *reinterpret_cast<uint4*>(yb + (size_t)row * EDIM + c) = p;
}

// out[row] = x[row,:] . Wm + bm
__global__ __launch_bounds__(256) void final_k(
    const float* __restrict__ x, const float* __restrict__ Wm,
    const float* __restrict__ bm, float* __restrict__ out)
{
    const int row = blockIdx.x * 4 + (threadIdx.x >> 6);
    const int lane = threadIdx.x & 63;
    const float* xr = x + (size_t)row * EDIM + lane * 8;
    const float* wr = Wm + lane * 8;
    float s = 0.f;
#pragma unroll
    for (int j = 0; j < 8; ++j) s = fmaf(xr[j], wr[j], s);
#pragma unroll
    for (int off = 32; off; off >>= 1) s += __shfl_xor(s, off, 64);
    if (lane == 0) out[row] = s + bm[0];
}

// ---------------------------------------------------------------------------
extern "C" void kernel_launch(void* const* d_in, const int* in_sizes, int n_in,
                              void* d_out, int out_size, void* d_ws, size_t ws_size,
                              hipStream_t stream)
{
    (void)in_sizes; (void)n_in; (void)out_size; (void)ws_size;
    const float* features = (const float*)d_in[0];
    const int*   targets  = (const int*)d_in[1];
    const float* emb      = (const float*)d_in[2];
    const float* Wf       = (const float*)d_in[3];
    const float* bfv      = (const float*)d_in[4];
    const float* a0Wo     = (const float*)d_in[5];
    const float* a0bo     = (const float*)d_in[6];
    const float* Wm       = (const float*)d_in[7];
    const float* bm       = (const float*)d_in[8];
    const float *ffg[3], *ffb[3], *W1[3], *b1[3], *W2[3], *b2[3];
    for (int i = 0; i < 3; ++i) {
        ffg[i] = (const float*)d_in[9 + 6 * i];
        ffb[i] = (const float*)d_in[10 + 6 * i];
        W1[i]  = (const float*)d_in[11 + 6 * i];
        b1[i]  = (const float*)d_in[12 + 6 * i];
        W2[i]  = (const float*)d_in[13 + 6 * i];
        b2[i]  = (const float*)d_in[14 + 6 * i];
    }
    const float *ag[2], *abp[2], *aWqkv[2], *aWo[2], *abo[2];
    for (int i = 0; i < 2; ++i) {
        ag[i]    = (const float*)d_in[27 + 5 * i];
        abp[i]   = (const float*)d_in[28 + 5 * i];
        aWqkv[i] = (const float*)d_in[29 + 5 * i];
        aWo[i]   = (const float*)d_in[30 + 5 * i];
        abo[i]   = (const float*)d_in[31 + 5 * i];
    }

    // ---- workspace carve-up ----
    char* wsc = (char*)d_ws;
    auto alloc = [&](size_t bytes) { char* p = wsc; wsc += bytes; return p; };
    ushort* WfvT  = (ushort*)alloc((size_t)ENW * INP * 2);       // 25.2 MB
    ushort* BTg   = (ushort*)alloc((size_t)NDOT * INP * 2);      // 6.3 MB
    float*  C0s   = (float*) alloc((size_t)NDOT * 4);
    float*  dsel  = (float*) alloc((size_t)BTOT * 128 * 4);      // 2.1 MB
    int*    perm  = (int*)   alloc((size_t)BTOT * 4);
    int*    boff  = (int*)   alloc(32 * 4);
    ushort* a0WoT = (ushort*)alloc((size_t)EDIM * EDIM * 2);
    ushort *W1T[3], *W2T[3], *WoT[2], *Wv_bf[2], *WcombT[2];
    for (int i = 0; i < 3; ++i) {
        W1T[i] = (ushort*)alloc((size_t)FFH * EDIM * 2);
        W2T[i] = (ushort*)alloc((size_t)EDIM * FFH * 2);
    }
    for (int i = 0; i < 2; ++i) {
        WoT[i]    = (ushort*)alloc((size_t)EDIM * EDIM * 2);
        Wv_bf[i]  = (ushort*)alloc((size_t)EDIM * EDIM * 2);
        WcombT[i] = (ushort*)alloc((size_t)EDIM * EDIM * 2);
    }
    ushort* featb = (ushort*)alloc((size_t)BTOT * INP * 2);      // 12.6 MB
    ushort* o_b   = (ushort*)alloc((size_t)BTOT * EDIM * 2);     // 4.2 MB
    float*  x     = (float*) alloc((size_t)BTOT * EDIM * 4);     // 8.4 MB
    ushort* xlnb  = (ushort*)alloc((size_t)BTOT * EDIM * 2);
    ushort* hb    = (ushort*)alloc((size_t)BTOT * FFH * 2);      // 8.4 MB
    ushort* vb    = (ushort*)alloc((size_t)BTOT * ENW * 2);      // 67 MB

    const dim3 blk(256, 1, 1);

    // ---- prep: 3 separate dispatches (r8 structure — measured faster) ----
    conv_all_k<<<3328, blk, 0, stream>>>(features, featb,
                                         aWqkv[0], aWqkv[1], Wv_bf[0], Wv_bf[1]);
    gproj_k<<<dim3(128, 9), blk, 0, stream>>>(Wf, bfv, emb, BTg, C0s,
                                              targets, perm, boff);

    TJobs tj;
    int ob = 0, ji = 0;
    auto addj = [&](const float* in, ushort* out, int ld, int c0, int R,
                    int gbx, int gby) {
        tj.j[ji++] = {in, out, ld, c0, R, gbx, ob};
        ob += gbx * gby;
    };
    addj(Wf, WfvT, KVW, ENW, INP, 128, 24);       // v-half of Wf (3072 blocks)
    addj(a0Wo, a0WoT, EDIM, 0, EDIM, 8, 8);
    for (int i = 0; i < 3; ++i) {
        addj(W1[i], W1T[i], FFH, 0, EDIM, 16, 8);
        addj(W2[i], W2T[i], EDIM, 0, FFH, 8, 16);
    }
    addj(aWo[0], WoT[0], EDIM, 0, EDIM, 8, 8);
    addj(aWo[1], WoT[1], EDIM, 0, EDIM, 8, 8);
    transpose_all_k<<<ob, blk, 0, stream>>>(tj);

    // ---- layer 0 ----
    const float CATT = -44.36141955583650f;   // -16*ln(16)
    gemm_dots_k<<<dim3(32, 16), blk, 0, stream>>>(featb, BTg, perm, boff,
                                                  C0s, dsel);
    for (int i = 0; i < 2; ++i)
        gemm_pipe64_k<false, true>
            <<<dim3(EDIM / 128, EDIM / 64), blk, 0, stream>>>(
            WoT[i], EDIM, Wv_bf[i], EDIM, WcombT[i], EDIM, EDIM,
            nullptr, nullptr, 0, CATT);
    gemm_v256_k<<<dim3(ENW / 256, BTOT / 256), dim3(512, 1, 1), 0, stream>>>(
        featb, WfvT, bfv + ENW, vb);
    attend0_k<<<BTOT, 512, 0, stream>>>(dsel, vb, o_b);
    gemm_pipe64_k<false, false>
        <<<dim3(EDIM / 128, BTOT / 64), blk, 0, stream>>>(
        o_b, EDIM, a0WoT, EDIM, x, EDIM, EDIM, a0bo, nullptr, 0, 1.f);

    auto ln = [&](const float* g, const float* b) {
        ln_k<<<BTOT / 4, blk, 0, stream>>>(x, g, b, xlnb);
    };
    auto ff = [&](int i) {
        ln(ffg[i], ffb[i]);
        gemm_pipe64_k<true, true>
            <<<dim3(FFH / 128, BTOT / 64), blk, 0, stream>>>(
            xlnb, EDIM, W1T[i], EDIM, hb, FFH, EDIM, b1[i], nullptr, 0, 1.f);
        gemm_pipe64_k<false, false>
            <<<dim3(EDIM / 128, BTOT / 64), blk, 0, stream>>>(
            hb, FFH, W2T[i], FFH, x, EDIM, FFH, b2[i], xlnb, EDIM, 1.f);
    };
    auto attn = [&](int i) {
        ln(ag[i], abp[i]);
        gemm_pipe64_k<false, false>
            <<<dim3(EDIM / 128, BTOT / 64), blk, 0, stream>>>(
            xlnb, EDIM, WcombT[i], EDIM, x, EDIM, EDIM, abo[i], xlnb, EDIM, 1.f);
    };

    ff(0);
    attn(0);
    ff(1);
    attn(1);
    ff(2);

    final_k<<<BTOT / 4, blk, 0, stream>>>(x, Wm, bm, (float*)d_out);
}

// Round 20
// 395.873 us; speedup vs baseline: 1.2692x; 1.0225x over previous
//
#include <hip/hip_runtime.h>
#include <math.h>

// MixedHead: B=16,T=256 -> BT=4096; INP=1536; E=512; H=8; N=16; D=64.
#define BTOT 4096
#define INP  1536
#define EDIM 512
#define NTOK 16
#define KVW  16384   // 2*E*N
#define ENW  8192    // E*N
#define FFH  1024    // 2*E
#define NDOT 2048    // 16 targets x 128 (h,m)

typedef __attribute__((ext_vector_type(8))) __bf16 bf16x8;
typedef __attribute__((ext_vector_type(4))) float f32x4;

__device__ __forceinline__ ushort f2bf(float f) {
    union { float f; unsigned u; } v; v.f = f;
    unsigned r = v.u + 0x7fffu + ((v.u >> 16) & 1u);
    return (ushort)(r >> 16);
}
__device__ __forceinline__ float bf2f(ushort h) {
    union { unsigned u; float f; } v; v.u = ((unsigned)h) << 16;
    return v.f;
}

// ---------------------------------------------------------------------------
// Transpose f32 [R][ld] (cols c0..) -> bf16 [C][R]. 10 jobs, one launch (r8).
// ---------------------------------------------------------------------------
__device__ __forceinline__ void transpose_body(
    const float* in, int ld, int c0, int R, ushort* out,
    int bx, int by, int tid)
{
    __shared__ float t[64][65];
    const int bc = bx * 64 + c0;
    const int br = by * 64;
#pragma unroll
    for (int it = 0; it < 16; ++it) {
        int idx = tid + it * 256;
        int r = idx >> 6, c = idx & 63;
        t[r][c] = in[(size_t)(br + r) * ld + bc + c];
    }
    __syncthreads();
    const int C0 = bx * 64;
#pragma unroll
    for (int it = 0; it < 4; ++it) {
        int idx = tid + it * 256;          // 1024 = 64 cols x 16 row-quads
        int cc = idx >> 4, rp = idx & 15;
        uint2 w2;
        w2.x = f2bf(t[4 * rp + 0][cc]) | ((unsigned)f2bf(t[4 * rp + 1][cc]) << 16);
        w2.y = f2bf(t[4 * rp + 2][cc]) | ((unsigned)f2bf(t[4 * rp + 3][cc]) << 16);
        *reinterpret_cast<uint2*>(out + (size_t)(C0 + cc) * R + br + 4 * rp) = w2;
    }
}

struct TJob { const float* in; ushort* out; int ld, c0, R, gbx, boffs; };
struct TJobs { TJob j[10]; };

__global__ __launch_bounds__(256) void transpose_all_k(TJobs jobs)
{
    const int b = blockIdx.x;
    int ji = 0;
    while (ji < 9 && b >= jobs.j[ji + 1].boffs) ++ji;
    TJob jb = jobs.j[ji];
    const int rel = b - jb.boffs;
    transpose_body(jb.in, jb.ld, jb.c0, jb.R, jb.out,
                   rel % jb.gbx, rel / jb.gbx, threadIdx.x);
}

// ---------------------------------------------------------------------------
// Merged converts (r8): [0,3072) features->bf16; [3072,3328) Wqkv v-slices.
// ---------------------------------------------------------------------------
__global__ __launch_bounds__(256) void conv_all_k(
    const float* __restrict__ features, ushort* __restrict__ featb,
    const float* __restrict__ wq0, const float* __restrict__ wq1,
    ushort* __restrict__ wv0, ushort* __restrict__ wv1)
{
    const int b = blockIdx.x;
    if (b < 3072) {
        const int i = b * 256 + threadIdx.x;          // < 786432
        const float4* p = reinterpret_cast<const float4*>(features) + 2 * (size_t)i;
        float4 a = p[0], c = p[1];
        uint4 o;
        o.x = f2bf(a.x) | ((unsigned)f2bf(a.y) << 16);
        o.y = f2bf(a.z) | ((unsigned)f2bf(a.w) << 16);
        o.z = f2bf(c.x) | ((unsigned)f2bf(c.y) << 16);
        o.w = f2bf(c.z) | ((unsigned)f2bf(c.w) << 16);
        reinterpret_cast<uint4*>(featb)[i] = o;
    } else {
        const int bb = b - 3072;
        const float* src = (bb >= 128) ? wq1 : wq0;
        ushort* dst = (bb >= 128) ? wv1 : wv0;
        const int idx = (bb & 127) * 256 + threadIdx.x;   // < 32768
        const int row = idx >> 6, c8 = (idx & 63) * 8;
        const float4* p = reinterpret_cast<const float4*>(
            src + (size_t)row * (3 * EDIM) + 2 * EDIM + c8);
        float4 a = p[0], c = p[1];
        uint4 o;
        o.x = f2bf(a.x) | ((unsigned)f2bf(a.y) << 16);
        o.y = f2bf(a.z) | ((unsigned)f2bf(a.w) << 16);
        o.z = f2bf(c.x) | ((unsigned)f2bf(c.y) << 16);
        o.w = f2bf(c.z) | ((unsigned)f2bf(c.w) << 16);
        *reinterpret_cast<uint4*>(dst + (size_t)row * EDIM + c8) = o;
    }
}

// ---------------------------------------------------------------------------
// G projection + embedded targets counting sort (r8, grid (128,9)).
// ---------------------------------------------------------------------------
__global__ __launch_bounds__(256) void gproj_k(
    const float* __restrict__ Wf, const float* __restrict__ bfv,
    const float* __restrict__ emb, ushort* __restrict__ BTg,
    float* __restrict__ C0s, const int* __restrict__ targets,
    int* __restrict__ perm, int* __restrict__ boff)
{
    if (blockIdx.y == 8) {
        if (blockIdx.x != 0) return;
        __shared__ int cnt[NTOK], off_s[NTOK], cur[NTOK];
        const int tid = threadIdx.x;
        if (tid < NTOK) cnt[tid] = 0;
        __syncthreads();
        for (int i = tid; i < BTOT; i += 256) atomicAdd(&cnt[targets[i]], 1);
        __syncthreads();
        if (tid == 0) {
            int s = 0;
            for (int b = 0; b < NTOK; ++b) { off_s[b] = s; cur[b] = s; s += cnt[b]; }
            for (int b = 0; b < NTOK; ++b) boff[b] = off_s[b];
            boff[NTOK] = s;
        }
        __syncthreads();
        for (int i = tid; i < BTOT; i += 256) {
            int t = targets[i];
            int p = atomicAdd(&cur[t], 1);
            perm[p] = i;
        }
        return;
    }

    const int hm = blockIdx.x;           // h*16 + m
    const int h = hm >> 4, m = hm & 15;
    const int l = threadIdx.x & 63, w = threadIdx.x >> 6;
    const int t = l & 15, isub = l >> 4;
    const int colb = m * 512 + h * 64;
    const int ibase = blockIdx.y * (INP / 8);

    float4 e[16];
#pragma unroll
    for (int q = 0; q < 16; ++q)
        e[q] = *reinterpret_cast<const float4*>(emb + t * EDIM + h * 64 + q * 4);

    const int n = t * 128 + hm;
    for (int i0 = ibase; i0 < ibase + INP / 8; i0 += 16) {
        const int i = i0 + w * 4 + isub;
        const float* wr = Wf + (size_t)i * KVW + colb;
        float acc = 0.f;
#pragma unroll
        for (int q = 0; q < 16; ++q) {
            float4 v4 = *reinterpret_cast<const float4*>(wr + q * 4);
            acc = fmaf(v4.x, e[q].x, fmaf(v4.y, e[q].y,
                  fmaf(v4.z, e[q].z, fmaf(v4.w, e[q].w, acc))));
        }
        BTg[(size_t)n * INP + i] = f2bf(acc);
    }
    if (blockIdx.y == 0 && w == 0 && isub == 0) {
        const float* br = bfv + colb;
        float acc = 0.f;
#pragma unroll
        for (int q = 0; q < 16; ++q) {
            float4 v4 = *reinterpret_cast<const float4*>(br + q * 4);
            acc = fmaf(v4.x, e[q].x, fmaf(v4.y, e[q].y,
                  fmaf(v4.z, e[q].z, fmaf(v4.w, e[q].w, acc))));
        }
        C0s[n] = 0.125f * acc;
    }
}

// ---------------------------------------------------------------------------
// 64x128 barrier-minimal pipelined layer GEMM (r17, proven: -21 us).
// 4 waves (2x2 of 32x64), LDS 48 KB -> 3 blocks/CU.
// ---------------------------------------------------------------------------
template <bool GELU, bool OUTBF>
__global__ __launch_bounds__(256, 3) void gemm_pipe64_k(
    const ushort* __restrict__ A, int lda,
    const ushort* __restrict__ BT, int ldb,
    void* __restrict__ Cp, int ldc, int K,
    const float* __restrict__ bias,
    const ushort* __restrict__ res, int ldr,
    float scale)
{
    __shared__ bf16x8 Asl[2][64][8];
    __shared__ bf16x8 Bsl[2][128][8];
    const int tid = threadIdx.x;
    const int l = tid & 63, w = tid >> 6;
    const int wm = w >> 1, wn = w & 1;      // 2 x 2 waves of 32x64
    const int brow = blockIdx.y * 64, bcol = blockIdx.x * 128;
    const int lr = l >> 3, ls = (l & 7) ^ lr;

    const ushort* Ab = A  + (size_t)(brow + w * 16 + lr) * lda + ls * 8;
    const ushort* Bb = BT + (size_t)(bcol + w * 32 + lr) * ldb + ls * 8;

#define STAGE_P(d, t) do { const int k0s = (t) * 64;                          \
    _Pragma("unroll")                                                          \
    for (int g = 0; g < 2; ++g)                                                \
        __builtin_amdgcn_global_load_lds(                                      \
            (const __attribute__((address_space(1))) void*)(Ab + (size_t)(g * 8) * lda + k0s), \
            (__attribute__((address_space(3))) void*)&Asl[d][w * 16 + g * 8][0], 16, 0, 0);    \
    _Pragma("unroll")                                                          \
    for (int g = 0; g < 4; ++g)                                                \
        __builtin_amdgcn_global_load_lds(                                      \
            (const __attribute__((address_space(1))) void*)(Bb + (size_t)(g * 8) * ldb + k0s), \
            (__attribute__((address_space(3))) void*)&Bsl[d][w * 32 + g * 8][0], 16, 0, 0);    \
} while (0)

#define RD_AP(dst, dd, kh) do {                                                \
    const int slot_ = ((kh) * 4 + (l >> 4)) ^ (l & 7);                         \
    _Pragma("unroll")                                                          \
    for (int mt = 0; mt < 2; ++mt)                                             \
        dst[mt] = Asl[dd][wm * 32 + mt * 16 + (l & 15)][slot_];                \
} while (0)

#define RD_BP(dd, kh) do {                                                     \
    const int slot_ = ((kh) * 4 + (l >> 4)) ^ (l & 7);                         \
    _Pragma("unroll")                                                          \
    for (int nt = 0; nt < 4; ++nt)                                             \
        bfr[nt][kh] = Bsl[dd][wn * 64 + nt * 16 + (l & 15)][slot_];            \
} while (0)

#define MFMA_P(af, kh) do {                                                    \
    __builtin_amdgcn_s_setprio(1);                                             \
    _Pragma("unroll")                                                          \
    for (int mt = 0; mt < 2; ++mt)                                             \
        _Pragma("unroll")                                                      \
        for (int nt = 0; nt < 4; ++nt)                                         \
            acc[mt][nt] = __builtin_amdgcn_mfma_f32_16x16x32_bf16(             \
                af[mt], bfr[nt][kh], acc[mt][nt], 0, 0, 0);                    \
    __builtin_amdgcn_s_setprio(0);                                             \
} while (0)

    f32x4 acc[2][4];
#pragma unroll
    for (int i = 0; i < 2; ++i)
#pragma unroll
        for (int j = 0; j < 4; ++j) acc[i][j] = (f32x4)0.f;

    // prologue: tiles 0 and 1 in flight (6 loads each); wait tile 0 only.
    STAGE_P(0, 0);
    STAGE_P(1, 1);
    asm volatile("s_waitcnt vmcnt(6)" ::: "memory");
    __builtin_amdgcn_s_barrier();

    bf16x8 aA[2], aB[2], bfr[4][2];
    RD_AP(aA, 0, 0);
    RD_BP(0, 0);

    const int NT = K / 64;
    for (int j = 0; j < NT; ++j) {
        const int d = j & 1;
        if (j > 0 && j + 1 < NT) STAGE_P(d ^ 1, j + 1);
        RD_AP(aB, d, 1);
        RD_BP(d, 1);
        MFMA_P(aA, 0);
        MFMA_P(aB, 1);
        __syncthreads();            // vmcnt(0)+lgkmcnt(0) drain: tile j+1
                                    // staged, all waves done with buffer d
        if (j + 1 < NT) {
            RD_AP(aA, d ^ 1, 0);
            RD_BP(d ^ 1, 0);
        }
    }

    const int cr = (l >> 4) * 4, cc = l & 15;
#pragma unroll
    for (int mt = 0; mt < 2; ++mt) {
#pragma unroll
        for (int nt = 0; nt < 4; ++nt) {
            const int gc = bcol + wn * 64 + nt * 16 + cc;
            const float bv = bias ? bias[gc] : 0.f;
#pragma unroll
            for (int r = 0; r < 4; ++r) {
                const size_t gr = (size_t)brow + wm * 32 + mt * 16 + cr + r;
                float v = acc[mt][nt][r] * scale + bv;
                if (GELU) v = 0.5f * v * (1.f + erff(v * 0.70710678118654752f));
                if (res) v += bf2f(res[gr * ldr + gc]);
                if (OUTBF) ((ushort*)Cp)[gr * ldc + gc] = f2bf(v);
                else       ((float*)Cp)[gr * ldc + gc]  = v;
            }
        }
    }
}

// ---------------------------------------------------------------------------
// Both Wcomb GEMMs in ONE launch (grid z=2): WcombT[z] = CATT*WoT[z]@Wv[z]^T.
// Exact pipe64 body (K=512, no bias/res, bf16 out). Local lda/ldb = EDIM so
// the shared macros expand correctly (fixes r19 compile error).
// ---------------------------------------------------------------------------
__global__ __launch_bounds__(256, 3) void gemm_wcomb_k(
    const ushort* __restrict__ A0, const ushort* __restrict__ B0,
    ushort* __restrict__ C0,
    const ushort* __restrict__ A1, const ushort* __restrict__ B1,
    ushort* __restrict__ C1, float scale)
{
    __shared__ bf16x8 Asl[2][64][8];
    __shared__ bf16x8 Bsl[2][128][8];
    const ushort* A  = blockIdx.z ? A1 : A0;
    const ushort* BT = blockIdx.z ? B1 : B0;
    ushort* Cp = blockIdx.z ? C1 : C0;
    const int lda = EDIM, ldb = EDIM;     // for the shared STAGE_P macro
    const int tid = threadIdx.x;
    const int l = tid & 63, w = tid >> 6;
    const int wm = w >> 1, wn = w & 1;
    const int brow = blockIdx.y * 64, bcol = blockIdx.x * 128;
    const int lr = l >> 3, ls = (l & 7) ^ lr;

    const ushort* Ab = A  + (size_t)(brow + w * 16 + lr) * lda + ls * 8;
    const ushort* Bb = BT + (size_t)(bcol + w * 32 + lr) * ldb + ls * 8;

    f32x4 acc[2][4];
#pragma unroll
    for (int i = 0; i < 2; ++i)
#pragma unroll
        for (int j = 0; j < 4; ++j) acc[i][j] = (f32x4)0.f;

    STAGE_P(0, 0);
    STAGE_P(1, 1);
    asm volatile("s_waitcnt vmcnt(6)" ::: "memory");
    __builtin_amdgcn_s_barrier();

    bf16x8 aA[2], aB[2], bfr[4][2];
    RD_AP(aA, 0, 0);
    RD_BP(0, 0);

    const int NT = EDIM / 64;   // 8
    for (int j = 0; j < NT; ++j) {
        const int d = j & 1;
        if (j > 0 && j + 1 < NT) STAGE_P(d ^ 1, j + 1);
        RD_AP(aB, d, 1);
        RD_BP(d, 1);
        MFMA_P(aA, 0);
        MFMA_P(aB, 1);
        __syncthreads();
        if (j + 1 < NT) {
            RD_AP(aA, d ^ 1, 0);
            RD_BP(d ^ 1, 0);
        }
    }

    const int cr = (l >> 4) * 4, cc = l & 15;
#pragma unroll
    for (int mt = 0; mt < 2; ++mt) {
#pragma unroll
        for (int nt = 0; nt < 4; ++nt) {
            const int gc = bcol + wn * 64 + nt * 16 + cc;
#pragma unroll
            for (int r = 0; r < 4; ++r) {
                const size_t gr = (size_t)brow + wm * 32 + mt * 16 + cr + r;
                Cp[gr * EDIM + gc] = f2bf(acc[mt][nt][r] * scale);
            }
        }
    }
}
#undef STAGE_P
#undef RD_AP
#undef RD_BP
#undef MFMA_P

// ---------------------------------------------------------------------------
// 256x256 v-GEMM, barrier-minimal pipeline, plain 2-D grid (r13/r14, proven).
// ---------------------------------------------------------------------------
__global__ __launch_bounds__(512, 2) void gemm_v256_k(
    const ushort* __restrict__ A,        // featb [BTOT][INP]
    const ushort* __restrict__ BT,       // WfvT [ENW][INP]
    const float* __restrict__ bias,      // bfv + ENW
    ushort* __restrict__ C)              // vb [BTOT][ENW]
{
    __shared__ bf16x8 lds[2][2][256][8];   // [dbuf][A/B][row][16B chunk]
    const int tid = threadIdx.x;
    const int l = tid & 63, w = tid >> 6;
    const int wm = w >> 2, wn = w & 3;      // 2 x 4 wave grid
    const int brow = blockIdx.y * 256, bcol = blockIdx.x * 256;
    const int lr = l >> 3, ls = (l & 7) ^ lr;

    const ushort* Ab = A  + (size_t)(brow + w * 8 + lr) * INP + ls * 8;
    const ushort* Bb = BT + (size_t)(bcol + w * 8 + lr) * INP + ls * 8;

#define STAGE_T(d, t) do { const int k0s = (t) * 64;                          \
    _Pragma("unroll")                                                          \
    for (int g = 0; g < 4; ++g)                                                \
        __builtin_amdgcn_global_load_lds(                                      \
            (const __attribute__((address_space(1))) void*)(Ab + (size_t)(g * 64) * INP + k0s), \
            (__attribute__((address_space(3))) void*)&lds[d][0][g * 64 + w * 8][0], 16, 0, 0);  \
    _Pragma("unroll")                                                          \
    for (int g = 0; g < 4; ++g)                                                \
        __builtin_amdgcn_global_load_lds(                                      \
            (const __attribute__((address_space(1))) void*)(Bb + (size_t)(g * 64) * INP + k0s), \
            (__attribute__((address_space(3))) void*)&lds[d][1][g * 64 + w * 8][0], 16, 0, 0);  \
} while (0)

#define RD_A(dst, dd, rh, kh) do {                                             \
    const int slot_ = ((kh) * 4 + (l >> 4)) ^ (l & 7);                         \
    _Pragma("unroll")                                                          \
    for (int mt = 0; mt < 4; ++mt)                                             \
        dst[mt] = lds[dd][0][wm * 128 + (rh) * 64 + mt * 16 + (l & 15)][slot_]; \
} while (0)

#define RD_B(dd, kh) do {                                                      \
    const int slot_ = ((kh) * 4 + (l >> 4)) ^ (l & 7);                         \
    _Pragma("unroll")                                                          \
    for (int nt = 0; nt < 4; ++nt)                                             \
        bfr[nt][kh] = lds[dd][1][wn * 64 + nt * 16 + (l & 15)][slot_];         \
} while (0)

#define MFMA4(base, af, kh) do {                                               \
    __builtin_amdgcn_s_setprio(1);                                             \
    _Pragma("unroll")                                                          \
    for (int mt = 0; mt < 4; ++mt)                                             \
        _Pragma("unroll")                                                      \
        for (int nt = 0; nt < 4; ++nt)                                         \
            acc[(base) + mt][nt] = __builtin_amdgcn_mfma_f32_16x16x32_bf16(    \
                af[mt], bfr[nt][kh], acc[(base) + mt][nt], 0, 0, 0);           \
    __builtin_amdgcn_s_setprio(0);                                             \
} while (0)

    f32x4 acc[8][4];
#pragma unroll
    for (int i = 0; i < 8; ++i)
#pragma unroll
        for (int j = 0; j < 4; ++j) acc[i][j] = (f32x4)0.f;

    // prologue: tiles 0 and 1 in flight; wait tile 0 only.
    STAGE_T(0, 0);
    STAGE_T(1, 1);
    asm volatile("s_waitcnt vmcnt(8)" ::: "memory");
    __builtin_amdgcn_s_barrier();

    bf16x8 aA[4], aB[4], bfr[4][2];
    RD_A(aA, 0, 0, 0);
    RD_B(0, 0);

    const int NT = INP / 64;   // 24
    for (int j = 0; j < NT; ++j) {
        const int d = j & 1;
        if (j > 0 && j + 1 < NT) STAGE_T(d ^ 1, j + 1);
        RD_A(aB, d, 0, 1);          // phase-1 frags
        RD_B(d, 1);
        MFMA4(0, aA, 0);            // phase 0 (rh0,kh0)
        RD_A(aA, d, 1, 0);          // phase-2 frags
        MFMA4(0, aB, 1);            // phase 1 (rh0,kh1)
        RD_A(aB, d, 1, 1);          // phase-3 frags
        MFMA4(4, aA, 0);            // phase 2 (rh1,kh0)
        MFMA4(4, aB, 1);            // phase 3 (rh1,kh1)
        __syncthreads();            // drains vmcnt(0): tile j+1 staged + all
                                    // waves done reading buffer d
        if (j + 1 < NT) {           // pre-issue next tile's phase-0 frags
            RD_A(aA, d ^ 1, 0, 0);
            RD_B(d ^ 1, 0);
        }
    }
#undef STAGE_T
#undef RD_A
#undef RD_B
#undef MFMA4

    const int cr = (l >> 4) * 4, cc = l & 15;
#pragma unroll
    for (int h = 0; h < 2; ++h)
#pragma unroll
        for (int mt = 0; mt < 4; ++mt)
#pragma unroll
            for (int nt = 0; nt < 4; ++nt) {
                const int gc = bcol + wn * 64 + nt * 16 + cc;
                const float bv = bias[gc];
#pragma unroll
                for (int r = 0; r < 4; ++r) {
                    const size_t gr = (size_t)brow + wm * 128 + h * 64 + mt * 16 + cr + r;
                    C[gr * ENW + gc] = f2bf(acc[h * 4 + mt][nt][r] + bv);
                }
            }
}

// ---------------------------------------------------------------------------
// Bucketed dots GEMM + log-softmax epilogue, barrier-minimal (r18, proven).
// ---------------------------------------------------------------------------
__global__ __launch_bounds__(256, 2) void gemm_dots_k(
    const ushort* __restrict__ A,
    const ushort* __restrict__ BT,
    const int* __restrict__ perm, const int* __restrict__ boff,
    const float* __restrict__ C0s, float* __restrict__ Csel)
{
    const int bucket = blockIdx.y;
    const int off = boff[bucket], end = boff[bucket + 1];
    const int tile = blockIdx.x;
    if (tile * 128 >= end - off) return;

    __shared__ bf16x8 Asl[2][128][8];
    __shared__ bf16x8 Bsl[2][128][8];
    const int tid = threadIdx.x;
    const int l = tid & 63, w = tid >> 6;
    const int wm = w >> 1, wn = w & 1;
    const int lr = l >> 3;
    const int ls = (l & 7) ^ lr;

    const ushort* Asrc[4];
#pragma unroll
    for (int i = 0; i < 4; ++i) {
        int rg = off + tile * 128 + w * 32 + lr + i * 8;
        Asrc[i] = A + (size_t)perm[rg < end ? rg : off] * INP + ls * 8;
    }
    const ushort* Bb = BT + (size_t)(bucket * 128 + w * 32 + lr) * INP + ls * 8;

#define DSTAGE(d, t) do { const int k0s = (t) * 64;                           \
    _Pragma("unroll")                                                          \
    for (int g = 0; g < 4; ++g)                                                \
        __builtin_amdgcn_global_load_lds(                                      \
            (const __attribute__((address_space(1))) void*)(Asrc[g] + k0s),    \
            (__attribute__((address_space(3))) void*)&Asl[d][w * 32 + g * 8][0], 16, 0, 0);    \
    _Pragma("unroll")                                                          \
    for (int g = 0; g < 4; ++g)                                                \
        __builtin_amdgcn_global_load_lds(                                      \
            (const __attribute__((address_space(1))) void*)(Bb + (size_t)(g * 8) * INP + k0s), \
            (__attribute__((address_space(3))) void*)&Bsl[d][w * 32 + g * 8][0], 16, 0, 0);    \
} while (0)

#define DRD_A(dst, dd, kh) do {                                                \
    const int slot_ = ((kh) * 4 + (l >> 4)) ^ (l & 7);                         \
    _Pragma("unroll")                                                          \
    for (int mt = 0; mt < 4; ++mt)                                             \
        dst[mt] = Asl[dd][wm * 64 + mt * 16 + (l & 15)][slot_];                \
} while (0)

#define DRD_B(dd, kh) do {                                                     \
    const int slot_ = ((kh) * 4 + (l >> 4)) ^ (l & 7);                         \
    _Pragma("unroll")                                                          \
    for (int nt = 0; nt < 4; ++nt)                                             \
        bfr[nt][kh] = Bsl[dd][wn * 64 + nt * 16 + (l & 15)][slot_];            \
} while (0)

#define DMFMA(af, kh) do {                                                     \
    __builtin_amdgcn_s_setprio(1);                                             \
    _Pragma("unroll")                                                          \
    for (int mt = 0; mt < 4; ++mt)                                             \
        _Pragma("unroll")                                                      \
        for (int nt = 0; nt < 4; ++nt)                                         \
            acc[mt][nt] = __builtin_amdgcn_mfma_f32_16x16x32_bf16(             \
                af[mt], bfr[nt][kh], acc[mt][nt], 0, 0, 0);                    \
    __builtin_amdgcn_s_setprio(0);                                             \
} while (0)

    f32x4 acc[4][4];
#pragma unroll
    for (int i = 0; i < 4; ++i)
#pragma unroll
        for (int j = 0; j < 4; ++j) acc[i][j] = (f32x4)0.f;

    DSTAGE(0, 0);
    DSTAGE(1, 1);
    asm volatile("s_waitcnt vmcnt(8)" ::: "memory");
    __builtin_amdgcn_s_barrier();

    bf16x8 aA[4], aB[4], bfr[4][2];
    DRD_A(aA, 0, 0);
    DRD_B(0, 0);

    const int NT = INP / 64;   // 24
    for (int j = 0; j < NT; ++j) {
        const int d = j & 1;
        if (j > 0 && j + 1 < NT) DSTAGE(d ^ 1, j + 1);
        DRD_A(aB, d, 1);
        DRD_B(d, 1);
        DMFMA(aA, 0);
        DMFMA(aB, 1);
        __syncthreads();
        if (j + 1 < NT) {
            DRD_A(aA, d ^ 1, 0);
            DRD_B(d ^ 1, 0);
        }
    }
#undef DSTAGE
#undef DRD_A
#undef DRD_B
#undef DMFMA

    const int cr = (l >> 4) * 4, cc = l & 15;
#pragma unroll
    for (int mt = 0; mt < 4; ++mt) {
#pragma unroll
        for (int nt = 0; nt < 4; ++nt) {
            const int gc = wn * 64 + nt * 16 + cc;
            const float bv = C0s[bucket * 128 + gc];
#pragma unroll
            for (int r = 0; r < 4; ++r) {
                float val = acc[mt][nt][r] * 0.125f + bv;
                float mx = val;
                mx = fmaxf(mx, __shfl_xor(mx, 1, 64));
                mx = fmaxf(mx, __shfl_xor(mx, 2, 64));
                mx = fmaxf(mx, __shfl_xor(mx, 4, 64));
                mx = fmaxf(mx, __shfl_xor(mx, 8, 64));
                float e = expf(val - mx);
                e += __shfl_xor(e, 1, 64);
                e += __shfl_xor(e, 2, 64);
                e += __shfl_xor(e, 4, 64);
                e += __shfl_xor(e, 8, 64);
                const float lse = mx + logf(e);
                int rg = off + tile * 128 + wm * 64 + mt * 16 + cr + r;
                int orow = perm[rg < end ? rg : off];
                Csel[(size_t)orow * 128 + gc] = val - lse;
            }
        }
    }
}

// ---------------------------------------------------------------------------
// Layer-0 attend: weights = dsel log-probs (precomputed), v bf16.
// ---------------------------------------------------------------------------
__global__ __launch_bounds__(512) void attend0_k(
    const float* __restrict__ dsel, const ushort* __restrict__ vb,
    ushort* __restrict__ o)
{
    const int bt = blockIdx.x;
    const int l  = threadIdx.x & 63;
    const int h  = threadIdx.x >> 6;
    const int dg = l & 7, mg = l >> 3;

    const float w0 = dsel[(size_t)bt * 128 + h * 16 + mg];
    const float w1 = dsel[(size_t)bt * 128 + h * 16 + 8 + mg];

    const ushort* base = vb + (size_t)bt * ENW + h * 64 + dg * 8;
    uint4 v0 = *reinterpret_cast<const uint4*>(base + (size_t)mg * EDIM);
    uint4 v1 = *reinterpret_cast<const uint4*>(base + (size_t)(8 + mg) * EDIM);
    const ushort* u0 = reinterpret_cast<const ushort*>(&v0);
    const ushort* u1 = reinterpret_cast<const ushort*>(&v1);
    float acc[8];
#pragma unroll
    for (int j = 0; j < 8; ++j)
        acc[j] = w0 * bf2f(u0[j]) + w1 * bf2f(u1[j]);
#pragma unroll
    for (int off = 8; off < 64; off <<= 1)
#pragma unroll
        for (int j = 0; j < 8; ++j) acc[j] += __shfl_xor(acc[j], off, 64);

    if (mg == 0) {
        uint4 pk;
        pk.x = f2bf(acc[0]) | ((unsigned)f2bf(acc[1]) << 16);
        pk.y = f2bf(acc[2]) | ((unsigned)f2bf(acc[3]) << 16);
        pk.z = f2bf(acc[4]) | ((unsigned)f2bf(acc[5]) << 16);
        pk.w = f2bf(acc[6]) | ((unsigned)f2bf(acc[7]) << 16);
        *reinterpret_cast<uint4*>(o + (size_t)bt * EDIM + h * 64 + dg * 8) = pk;
    }
}

// ---------------------------------------------------------------------------
// Row LayerNorm over E=512: one wave per row; emits bf16 ONLY (r14).
// ---------------------------------------------------------------------------
__global__ __launch_bounds__(256) void ln_k(
    const float* __restrict__ x, const float* __restrict__ g,
    const float* __restrict__ b, ushort* __restrict__ yb)
{
    const int row = blockIdx.x * 4 + (threadIdx.x >> 6);
    const int lane = threadIdx.x & 63;
    const float* xr = x + (size_t)row * EDIM + lane * 8;
    float4 a0 = *reinterpret_cast<const float4*>(xr);
    float4 a1 = *reinterpret_cast<const float4*>(xr + 4);
    float v[8] = {a0.x, a0.y, a0.z, a0.w, a1.x, a1.y, a1.z, a1.w};

    float s = 0.f;
#pragma unroll
    for (int j = 0; j < 8; ++j) s += v[j];
#pragma unroll
    for (int off = 32; off; off >>= 1) s += __shfl_xor(s, off, 64);
    const float m = s * (1.f / 512.f);

    float q = 0.f;
#pragma unroll
    for (int j = 0; j < 8; ++j) { float d = v[j] - m; q = fmaf(d, d, q); }
#pragma unroll
    for (int off = 32; off; off >>= 1) q += __shfl_xor(q, off, 64);
    const float inv = rsqrtf(q * (1.f / 512.f) + 1e-5f);

    const int c = lane * 8;
    float4 g0 = *reinterpret_cast<const float4*>(g + c);
    float4 g1 = *reinterpret_cast<const float4*>(g + c + 4);
    float4 b0 = *reinterpret_cast<const float4*>(b + c);
    float4 b1 = *reinterpret_cast<const float4*>(b + c + 4);
    float gg[8] = {g0.x, g0.y, g0.z, g0.w, g1.x, g1.y, g1.z, g1.w};
    float bb[8] = {b0.x, b0.y, b0.z, b0.w, b1.x, b1.y, b1.z, b1.w};
    float out[8];
#pragma unroll
    for (int j = 0; j < 8; ++j) out[j] = (v[j] - m) * inv * gg[j] + bb[j];
    uint4 p;
    p.x = f2bf(out[0]) | ((unsigned)f2bf(out[1]) << 16);
    p.y = f2bf(out[2]) | ((unsigned)f2bf(out[3]) << 16);
    p.z = f2bf(out[4]) | ((unsigned)f2bf(out[5]) << 16);
    p.w = f2bf(out[6]) | ((unsigned)f2bf(out[7]) << 16);
    *reinterpret_cast<uint4*>(yb + (size_t)row * EDIM + c) = p;
}

// out[row] = x[row,:] . Wm + bm
__global__ __launch_bounds__(256) void final_k(
    const float* __restrict__ x, const float* __restrict__ Wm,
    const float* __restrict__ bm, float* __restrict__ out)
{
    const int row = blockIdx.x * 4 + (threadIdx.x >> 6);
    const int lane = threadIdx.x & 63;
    const float* xr = x + (size_t)row * EDIM + lane * 8;
    const float* wr = Wm + lane * 8;
    float s = 0.f;
#pragma unroll
    for (int j = 0; j < 8; ++j) s = fmaf(xr[j], wr[j], s);
#pragma unroll
    for (int off = 32; off; off >>= 1) s += __shfl_xor(s, off, 64);
    if (lane == 0) out[row] = s + bm[0];
}

// ---------------------------------------------------------------------------
extern "C" void kernel_launch(void* const* d_in, const int* in_sizes, int n_in,
                              void* d_out, int out_size, void* d_ws, size_t ws_size,
                              hipStream_t stream)
{
    (void)in_sizes; (void)n_in; (void)out_size; (void)ws_size;
    const float* features = (const float*)d_in[0];
    const int*   targets  = (const int*)d_in[1];
    const float* emb      = (const float*)d_in[2];
    const float* Wf       = (const float*)d_in[3];
    const float* bfv      = (const float*)d_in[4];
    const float* a0Wo     = (const float*)d_in[5];
    const float* a0bo     = (const float*)d_in[6];
    const float* Wm       = (const float*)d_in[7];
    const float* bm       = (const float*)d_in[8];
    const float *ffg[3], *ffb[3], *W1[3], *b1[3], *W2[3], *b2[3];
    for (int i = 0; i < 3; ++i) {
        ffg[i] = (const float*)d_in[9 + 6 * i];
        ffb[i] = (const float*)d_in[10 + 6 * i];
        W1[i]  = (const float*)d_in[11 + 6 * i];
        b1[i]  = (const float*)d_in[12 + 6 * i];
        W2[i]  = (const float*)d_in[13 + 6 * i];
        b2[i]  = (const float*)d_in[14 + 6 * i];
    }
    const float *ag[2], *abp[2], *aWqkv[2], *aWo[2], *abo[2];
    for (int i = 0; i < 2; ++i) {
        ag[i]    = (const float*)d_in[27 + 5 * i];
        abp[i]   = (const float*)d_in[28 + 5 * i];
        aWqkv[i] = (const float*)d_in[29 + 5 * i];
        aWo[i]   = (const float*)d_in[30 + 5 * i];
        abo[i]   = (const float*)d_in[31 + 5 * i];
    }

    // ---- workspace carve-up ----
    char* wsc = (char*)d_ws;
    auto alloc = [&](size_t bytes) { char* p = wsc; wsc += bytes; return p; };
    ushort* WfvT  = (ushort*)alloc((size_t)ENW * INP * 2);       // 25.2 MB
    ushort* BTg   = (ushort*)alloc((size_t)NDOT * INP * 2);      // 6.3 MB
    float*  C0s   = (float*) alloc((size_t)NDOT * 4);
    float*  dsel  = (float*) alloc((size_t)BTOT * 128 * 4);      // 2.1 MB
    int*    perm  = (int*)   alloc((size_t)BTOT * 4);
    int*    boff  = (int*)   alloc(32 * 4);
    ushort* a0WoT = (ushort*)alloc((size_t)EDIM * EDIM * 2);
    ushort *W1T[3], *W2T[3], *WoT[2], *Wv_bf[2], *WcombT[2];
    for (int i = 0; i < 3; ++i) {
        W1T[i] = (ushort*)alloc((size_t)FFH * EDIM * 2);
        W2T[i] = (ushort*)alloc((size_t)EDIM * FFH * 2);
    }
    for (int i = 0; i < 2; ++i) {
        WoT[i]    = (ushort*)alloc((size_t)EDIM * EDIM * 2);
        Wv_bf[i]  = (ushort*)alloc((size_t)EDIM * EDIM * 2);
        WcombT[i] = (ushort*)alloc((size_t)EDIM * EDIM * 2);
    }
    ushort* featb = (ushort*)alloc((size_t)BTOT * INP * 2);      // 12.6 MB
    ushort* o_b   = (ushort*)alloc((size_t)BTOT * EDIM * 2);     // 4.2 MB
    float*  x     = (float*) alloc((size_t)BTOT * EDIM * 4);     // 8.4 MB
    ushort* xlnb  = (ushort*)alloc((size_t)BTOT * EDIM * 2);
    ushort* hb    = (ushort*)alloc((size_t)BTOT * FFH * 2);      // 8.4 MB
    ushort* vb    = (ushort*)alloc((size_t)BTOT * ENW * 2);      // 67 MB

    const dim3 blk(256, 1, 1);

    // ---- prep: 3 separate dispatches (r8 structure — measured faster) ----
    conv_all_k<<<3328, blk, 0, stream>>>(features, featb,
                                         aWqkv[0], aWqkv[1], Wv_bf[0], Wv_bf[1]);
    gproj_k<<<dim3(128, 9), blk, 0, stream>>>(Wf, bfv, emb, BTg, C0s,
                                              targets, perm, boff);

    TJobs tj;
    int ob = 0, ji = 0;
    auto addj = [&](const float* in, ushort* out, int ld, int c0, int R,
                    int gbx, int gby) {
        tj.j[ji++] = {in, out, ld, c0, R, gbx, ob};
        ob += gbx * gby;
    };
    addj(Wf, WfvT, KVW, ENW, INP, 128, 24);       // v-half of Wf (3072 blocks)
    addj(a0Wo, a0WoT, EDIM, 0, EDIM, 8, 8);
    for (int i = 0; i < 3; ++i) {
        addj(W1[i], W1T[i], FFH, 0, EDIM, 16, 8);
        addj(W2[i], W2T[i], EDIM, 0, FFH, 8, 16);
    }
    addj(aWo[0], WoT[0], EDIM, 0, EDIM, 8, 8);
    addj(aWo[1], WoT[1], EDIM, 0, EDIM, 8, 8);
    transpose_all_k<<<ob, blk, 0, stream>>>(tj);

    // ---- layer 0 ----
    const float CATT = -44.36141955583650f;   // -16*ln(16)
    gemm_dots_k<<<dim3(32, 16), blk, 0, stream>>>(featb, BTg, perm, boff,
                                                  C0s, dsel);
    gemm_wcomb_k<<<dim3(EDIM / 128, EDIM / 64, 2), blk, 0, stream>>>(
        WoT[0], Wv_bf[0], WcombT[0], WoT[1], Wv_bf[1], WcombT[1], CATT);
    gemm_v256_k<<<dim3(ENW / 256, BTOT / 256), dim3(512, 1, 1), 0, stream>>>(
        featb, WfvT, bfv + ENW, vb);
    attend0_k<<<BTOT, 512, 0, stream>>>(dsel, vb, o_b);
    gemm_pipe64_k<false, false>
        <<<dim3(EDIM / 128, BTOT / 64), blk, 0, stream>>>(
        o_b, EDIM, a0WoT, EDIM, x, EDIM, EDIM, a0bo, nullptr, 0, 1.f);

    auto ln = [&](const float* g, const float* b) {
        ln_k<<<BTOT / 4, blk, 0, stream>>>(x, g, b, xlnb);
    };
    auto ff = [&](int i) {
        ln(ffg[i], ffb[i]);
        gemm_pipe64_k<true, true>
            <<<dim3(FFH / 128, BTOT / 64), blk, 0, stream>>>(
            xlnb, EDIM, W1T[i], EDIM, hb, FFH, EDIM, b1[i], nullptr, 0, 1.f);
        gemm_pipe64_k<false, false>
            <<<dim3(EDIM / 128, BTOT / 64), blk, 0, stream>>>(
            hb, FFH, W2T[i], FFH, x, EDIM, FFH, b2[i], xlnb, EDIM, 1.f);
    };
    auto attn = [&](int i) {
        ln(ag[i], abp[i]);
        gemm_pipe64_k<false, false>
            <<<dim3(EDIM / 128, BTOT / 64), blk, 0, stream>>>(
            xlnb, EDIM, WcombT[i], EDIM, x, EDIM, EDIM, abo[i], xlnb, EDIM, 1.f);
    };

    ff(0);
    attn(0);
    ff(1);
    attn(1);
    ff(2);

    final_k<<<BTOT / 4, blk, 0, stream>>>(x, Wm, bm, (float*)d_out);
}